// Round 1
// baseline (374.527 us; speedup 1.0000x reference)
//
#include <hip/hip_runtime.h>
#include <math.h>

#define NB 4096
#define ND 512
#define BMT 64
#define BNT 64
#define BKT 32
#define NSPLIT 16
#define JSPAN (NB / NSPLIT)   /* 256 */
#define NTILE (JSPAN / BNT)   /* 4 */
#define KNB 5

// ---------- helpers: (value,index) predicated min/max ----------
__device__ __forceinline__ void sel_min(float av, int ai, float bv, int bi, float& ov, int& oi) {
    bool p = av <= bv;
    ov = p ? av : bv;
    oi = p ? ai : bi;
}
__device__ __forceinline__ void sel_max(float av, int ai, float bv, int bi, float& ov, int& oi) {
    bool p = av >= bv;
    ov = p ? av : bv;
    oi = p ? ai : bi;
}

// Merge two sorted-ascending 5-lists, keep 5 smallest (static network).
// Identity: c_i = min( a_i, b_i, min_{j=0..i-1} max(a_j, b_{i-1-j}) )
__device__ __forceinline__ void merge5(float (&a)[5], int (&ai)[5],
                                       const float (&b)[5], const int (&bi)[5]) {
    float c[5]; int ci[5];
    float m; int mi;
    // c0
    sel_min(a[0], ai[0], b[0], bi[0], c[0], ci[0]);
    // c1
    sel_max(a[0], ai[0], b[0], bi[0], m, mi);
    sel_min(a[1], ai[1], m, mi, c[1], ci[1]);
    sel_min(c[1], ci[1], b[1], bi[1], c[1], ci[1]);
    // c2
    sel_max(a[1], ai[1], b[0], bi[0], m, mi);
    sel_min(a[2], ai[2], m, mi, c[2], ci[2]);
    sel_max(a[0], ai[0], b[1], bi[1], m, mi);
    sel_min(c[2], ci[2], m, mi, c[2], ci[2]);
    sel_min(c[2], ci[2], b[2], bi[2], c[2], ci[2]);
    // c3
    sel_max(a[2], ai[2], b[0], bi[0], m, mi);
    sel_min(a[3], ai[3], m, mi, c[3], ci[3]);
    sel_max(a[1], ai[1], b[1], bi[1], m, mi);
    sel_min(c[3], ci[3], m, mi, c[3], ci[3]);
    sel_max(a[0], ai[0], b[2], bi[2], m, mi);
    sel_min(c[3], ci[3], m, mi, c[3], ci[3]);
    sel_min(c[3], ci[3], b[3], bi[3], c[3], ci[3]);
    // c4
    sel_max(a[3], ai[3], b[0], bi[0], m, mi);
    sel_min(a[4], ai[4], m, mi, c[4], ci[4]);
    sel_max(a[2], ai[2], b[1], bi[1], m, mi);
    sel_min(c[4], ci[4], m, mi, c[4], ci[4]);
    sel_max(a[1], ai[1], b[2], bi[2], m, mi);
    sel_min(c[4], ci[4], m, mi, c[4], ci[4]);
    sel_max(a[0], ai[0], b[3], bi[3], m, mi);
    sel_min(c[4], ci[4], m, mi, c[4], ci[4]);
    sel_min(c[4], ci[4], b[4], bi[4], c[4], ci[4]);
#pragma unroll
    for (int s = 0; s < 5; ++s) { a[s] = c[s]; ai[s] = ci[s]; }
}

// Insert (key, j) into sorted-ascending top-5 list (registers, static indices).
__device__ __forceinline__ void top5_insert(float (&tv)[5], int (&ti)[5], float key, int j) {
    if (key < tv[4]) {
        tv[4] = key; ti[4] = j;
#pragma unroll
        for (int s = 4; s >= 1; --s) {
            if (tv[s] < tv[s - 1]) {
                float tf = tv[s]; tv[s] = tv[s - 1]; tv[s - 1] = tf;
                int tt = ti[s]; ti[s] = ti[s - 1]; ti[s - 1] = tt;
            }
        }
    }
}

// ---------- kernel A: per-row sum of squares ----------
__global__ __launch_bounds__(256) void sumsq_kernel(const float* __restrict__ M,
                                                    float* __restrict__ sq) {
    const int row = blockIdx.x * 4 + (threadIdx.x >> 6);
    const int lane = threadIdx.x & 63;
    const float* p = M + (size_t)row * ND + lane * 8;
    float4 v0 = *(const float4*)p;
    float4 v1 = *(const float4*)(p + 4);
    float s = v0.x * v0.x + v0.y * v0.y + v0.z * v0.z + v0.w * v0.w
            + v1.x * v1.x + v1.y * v1.y + v1.z * v1.z + v1.w * v1.w;
#pragma unroll
    for (int off = 32; off >= 1; off >>= 1) s += __shfl_down(s, off, 64);
    if (lane == 0) sq[row] = s;
}

// ---------- kernel B: fused fp32 Gram-tile + per-row top-5 ----------
__global__ __launch_bounds__(256) void dist_topk_kernel(const float* __restrict__ M,
                                                        const float* __restrict__ sq,
                                                        float* __restrict__ tvals,
                                                        int* __restrict__ tidx) {
    __shared__ float As[BKT][BMT];
    __shared__ float Bs[BKT][BNT];
    const int tid = threadIdx.x;
    const int tx = tid & 15;
    const int ty = tid >> 4;
    const int i0 = blockIdx.x * BMT;
    const int jbase = blockIdx.y * JSPAN;

    const int lrow = tid >> 2;         // 0..63
    const int lc = (tid & 3) << 3;     // 0,8,16,24

    float tv[4][5]; int ti[4][5];
#pragma unroll
    for (int r = 0; r < 4; ++r) {
#pragma unroll
        for (int s = 0; s < 5; ++s) { tv[r][s] = INFINITY; ti[r][s] = 0; }
    }

    const float* Arow = M + (size_t)(i0 + lrow) * ND + lc;

    for (int jt = 0; jt < NTILE; ++jt) {
        const int j0 = jbase + jt * BNT;
        const float* Brow = M + (size_t)(j0 + lrow) * ND + lc;

        float acc[4][4];
#pragma unroll
        for (int x = 0; x < 4; ++x) {
#pragma unroll
            for (int y = 0; y < 4; ++y) acc[x][y] = 0.f;
        }

        for (int kc = 0; kc < ND; kc += BKT) {
            float4 a0 = *(const float4*)(Arow + kc);
            float4 a1 = *(const float4*)(Arow + kc + 4);
            float4 b0 = *(const float4*)(Brow + kc);
            float4 b1 = *(const float4*)(Brow + kc + 4);
            __syncthreads();  // previous chunk's reads done before overwrite
            As[lc + 0][lrow] = a0.x; As[lc + 1][lrow] = a0.y;
            As[lc + 2][lrow] = a0.z; As[lc + 3][lrow] = a0.w;
            As[lc + 4][lrow] = a1.x; As[lc + 5][lrow] = a1.y;
            As[lc + 6][lrow] = a1.z; As[lc + 7][lrow] = a1.w;
            Bs[lc + 0][lrow] = b0.x; Bs[lc + 1][lrow] = b0.y;
            Bs[lc + 2][lrow] = b0.z; Bs[lc + 3][lrow] = b0.w;
            Bs[lc + 4][lrow] = b1.x; Bs[lc + 5][lrow] = b1.y;
            Bs[lc + 6][lrow] = b1.z; Bs[lc + 7][lrow] = b1.w;
            __syncthreads();
#pragma unroll
            for (int k = 0; k < BKT; ++k) {
                float ar0 = As[k][ty * 4 + 0], ar1 = As[k][ty * 4 + 1];
                float ar2 = As[k][ty * 4 + 2], ar3 = As[k][ty * 4 + 3];
                float br0 = Bs[k][tx * 4 + 0], br1 = Bs[k][tx * 4 + 1];
                float br2 = Bs[k][tx * 4 + 2], br3 = Bs[k][tx * 4 + 3];
                acc[0][0] = fmaf(ar0, br0, acc[0][0]);
                acc[0][1] = fmaf(ar0, br1, acc[0][1]);
                acc[0][2] = fmaf(ar0, br2, acc[0][2]);
                acc[0][3] = fmaf(ar0, br3, acc[0][3]);
                acc[1][0] = fmaf(ar1, br0, acc[1][0]);
                acc[1][1] = fmaf(ar1, br1, acc[1][1]);
                acc[1][2] = fmaf(ar1, br2, acc[1][2]);
                acc[1][3] = fmaf(ar1, br3, acc[1][3]);
                acc[2][0] = fmaf(ar2, br0, acc[2][0]);
                acc[2][1] = fmaf(ar2, br1, acc[2][1]);
                acc[2][2] = fmaf(ar2, br2, acc[2][2]);
                acc[2][3] = fmaf(ar2, br3, acc[2][3]);
                acc[3][0] = fmaf(ar3, br0, acc[3][0]);
                acc[3][1] = fmaf(ar3, br1, acc[3][1]);
                acc[3][2] = fmaf(ar3, br2, acc[3][2]);
                acc[3][3] = fmaf(ar3, br3, acc[3][3]);
            }
        }

        // selection key: d2 - sq[i] = sq[j] - 2*dot  (monotone per row i)
#pragma unroll
        for (int nj = 0; nj < 4; ++nj) {
            const int j = j0 + tx * 4 + nj;
            const float sqj = sq[j];
#pragma unroll
            for (int mi = 0; mi < 4; ++mi) {
                float key = fmaf(-2.f, acc[mi][nj], sqj);
                if (j == i0 + ty * 4 + mi) key = INFINITY;  // mask diagonal
                top5_insert(tv[mi], ti[mi], key, j);
            }
        }
    }

    // merge top-5 lists across the 16 lanes sharing each row (lanes ty*16+tx)
#pragma unroll
    for (int m = 1; m <= 8; m <<= 1) {
#pragma unroll
        for (int r = 0; r < 4; ++r) {
            float bv[5]; int bi2[5];
#pragma unroll
            for (int s = 0; s < 5; ++s) {
                bv[s] = __shfl_xor(tv[r][s], m, 64);
                bi2[s] = __shfl_xor(ti[r][s], m, 64);
            }
            merge5(tv[r], ti[r], bv, bi2);
        }
    }

    if (tx == 0) {
#pragma unroll
        for (int r = 0; r < 4; ++r) {
            const int row = i0 + ty * 4 + r;
            const size_t base = ((size_t)row * NSPLIT + blockIdx.y) * KNB;
#pragma unroll
            for (int s = 0; s < 5; ++s) {
                tvals[base + s] = tv[r][s];
                tidx[base + s] = ti[r][s];
            }
        }
    }
}

// ---------- kernel C: merge splits, gather neighbors, std(ddof=1), MSE partial ----------
__global__ __launch_bounds__(256) void loss_kernel(const float* __restrict__ M,
                                                   const float* __restrict__ V1,
                                                   const float* __restrict__ tvals,
                                                   const int* __restrict__ tidx,
                                                   float* __restrict__ partial) {
    const int i = blockIdx.x;
    const int tid = threadIdx.x;
    __shared__ float svals[NSPLIT * KNB];
    __shared__ int sidx[NSPLIT * KNB];
    __shared__ int nb[KNB];
    __shared__ float wsum[4];
    if (tid < NSPLIT * KNB) {
        svals[tid] = tvals[(size_t)i * (NSPLIT * KNB) + tid];
        sidx[tid] = tidx[(size_t)i * (NSPLIT * KNB) + tid];
    }
    __syncthreads();
    if (tid == 0) {
        // 5 smallest of 80 candidates; tie-break lower index (matches stable top_k)
        for (int s = 0; s < KNB; ++s) {
            float best = INFINITY; int bj = 0x7fffffff; int bpos = 0;
            for (int t = 0; t < NSPLIT * KNB; ++t) {
                float v = svals[t];
                int jj = sidx[t];
                if (v < best || (v == best && jj < bj)) { best = v; bj = jj; bpos = t; }
            }
            nb[s] = bj;
            svals[bpos] = INFINITY;
        }
    }
    __syncthreads();
    const int n0 = nb[0], n1 = nb[1], n2 = nb[2], n3 = nb[3], n4 = nb[4];
    float lsum = 0.f;
#pragma unroll
    for (int rep = 0; rep < ND / 256; ++rep) {
        const int d = rep * 256 + tid;
        float x0 = M[(size_t)n0 * ND + d];
        float x1 = M[(size_t)n1 * ND + d];
        float x2 = M[(size_t)n2 * ND + d];
        float x3 = M[(size_t)n3 * ND + d];
        float x4 = M[(size_t)n4 * ND + d];
        float mean = (x0 + x1 + x2 + x3 + x4) * 0.2f;
        float e0 = x0 - mean, e1 = x1 - mean, e2 = x2 - mean, e3 = x3 - mean, e4 = x4 - mean;
        float var = (e0 * e0 + e1 * e1 + e2 * e2 + e3 * e3 + e4 * e4) * 0.25f;  // ddof=1
        float nstd = sqrtf(var);
        float pred = expf(0.5f * V1[(size_t)i * ND + d]);  // sqrt(exp(v))
        float df = pred - nstd;
        lsum = fmaf(df, df, lsum);
    }
#pragma unroll
    for (int off = 32; off >= 1; off >>= 1) lsum += __shfl_down(lsum, off, 64);
    if ((tid & 63) == 0) wsum[tid >> 6] = lsum;
    __syncthreads();
    if (tid == 0) partial[i] = (wsum[0] + wsum[1]) + (wsum[2] + wsum[3]);
}

// ---------- kernel D: deterministic final reduction ----------
__global__ __launch_bounds__(256) void finalize_kernel(const float* __restrict__ partial,
                                                       float* __restrict__ out) {
    const int tid = threadIdx.x;
    double s = 0.0;
    for (int i = tid; i < NB; i += 256) s += (double)partial[i];
#pragma unroll
    for (int off = 32; off >= 1; off >>= 1) s += __shfl_down(s, off, 64);
    __shared__ double dsum[4];
    if ((tid & 63) == 0) dsum[tid >> 6] = s;
    __syncthreads();
    if (tid == 0)
        out[0] = (float)(((dsum[0] + dsum[1]) + (dsum[2] + dsum[3])) / ((double)NB * (double)ND));
}

extern "C" void kernel_launch(void* const* d_in, const int* in_sizes, int n_in,
                              void* d_out, int out_size, void* d_ws, size_t ws_size,
                              hipStream_t stream) {
    const float* mean1 = (const float*)d_in[0];
    const float* var1 = (const float*)d_in[1];
    // d_in[2], d_in[3] (mean2, var2) are unused by the reference.

    float* ws = (float*)d_ws;
    float* sq = ws;                                         // NB floats
    float* tvals = ws + NB;                                 // NB*NSPLIT*KNB floats
    int* tidx = (int*)(tvals + (size_t)NB * NSPLIT * KNB);  // NB*NSPLIT*KNB ints
    float* partial = (float*)(tidx + (size_t)NB * NSPLIT * KNB);  // NB floats
    float* out = (float*)d_out;

    sumsq_kernel<<<NB / 4, 256, 0, stream>>>(mean1, sq);
    dist_topk_kernel<<<dim3(NB / BMT, NSPLIT), 256, 0, stream>>>(mean1, sq, tvals, tidx);
    loss_kernel<<<NB, 256, 0, stream>>>(mean1, var1, tvals, tidx, partial);
    finalize_kernel<<<1, 256, 0, stream>>>(partial, out);
}

// Round 2
// 205.876 us; speedup vs baseline: 1.8192x; 1.8192x over previous
//
#include <hip/hip_runtime.h>
#include <math.h>

#define NB 4096
#define ND 512
#define BM 64
#define BN 256
#define BK 32
#define NSPLIT 16
#define JSPAN (NB / NSPLIT) /* 256 */
#define KNB 5
#define PAD 40 /* bf16 elems per LDS row: 32 + 8 pad -> 80B stride, conflict-free reads */

typedef float f32x4 __attribute__((ext_vector_type(4)));
typedef short bf16x8 __attribute__((ext_vector_type(8)));

// ---------- helpers: (value,index) predicated min/max ----------
__device__ __forceinline__ void sel_min(float av, int ai, float bv, int bi, float& ov, int& oi) {
    bool p = av <= bv;
    ov = p ? av : bv;
    oi = p ? ai : bi;
}
__device__ __forceinline__ void sel_max(float av, int ai, float bv, int bi, float& ov, int& oi) {
    bool p = av >= bv;
    ov = p ? av : bv;
    oi = p ? ai : bi;
}

// Merge two sorted-ascending 5-lists, keep 5 smallest (static network).
__device__ __forceinline__ void merge5(float (&a)[5], int (&ai)[5],
                                       const float (&b)[5], const int (&bi)[5]) {
    float c[5]; int ci[5];
    float m; int mi;
    sel_min(a[0], ai[0], b[0], bi[0], c[0], ci[0]);
    sel_max(a[0], ai[0], b[0], bi[0], m, mi);
    sel_min(a[1], ai[1], m, mi, c[1], ci[1]);
    sel_min(c[1], ci[1], b[1], bi[1], c[1], ci[1]);
    sel_max(a[1], ai[1], b[0], bi[0], m, mi);
    sel_min(a[2], ai[2], m, mi, c[2], ci[2]);
    sel_max(a[0], ai[0], b[1], bi[1], m, mi);
    sel_min(c[2], ci[2], m, mi, c[2], ci[2]);
    sel_min(c[2], ci[2], b[2], bi[2], c[2], ci[2]);
    sel_max(a[2], ai[2], b[0], bi[0], m, mi);
    sel_min(a[3], ai[3], m, mi, c[3], ci[3]);
    sel_max(a[1], ai[1], b[1], bi[1], m, mi);
    sel_min(c[3], ci[3], m, mi, c[3], ci[3]);
    sel_max(a[0], ai[0], b[2], bi[2], m, mi);
    sel_min(c[3], ci[3], m, mi, c[3], ci[3]);
    sel_min(c[3], ci[3], b[3], bi[3], c[3], ci[3]);
    sel_max(a[3], ai[3], b[0], bi[0], m, mi);
    sel_min(a[4], ai[4], m, mi, c[4], ci[4]);
    sel_max(a[2], ai[2], b[1], bi[1], m, mi);
    sel_min(c[4], ci[4], m, mi, c[4], ci[4]);
    sel_max(a[1], ai[1], b[2], bi[2], m, mi);
    sel_min(c[4], ci[4], m, mi, c[4], ci[4]);
    sel_max(a[0], ai[0], b[3], bi[3], m, mi);
    sel_min(c[4], ci[4], m, mi, c[4], ci[4]);
    sel_min(c[4], ci[4], b[4], bi[4], c[4], ci[4]);
#pragma unroll
    for (int s = 0; s < 5; ++s) { a[s] = c[s]; ai[s] = ci[s]; }
}

__device__ __forceinline__ void cswap(float& a, int& ai, float& b, int& bi) {
    float mn, mx; int mni, mxi;
    sel_min(a, ai, b, bi, mn, mni);
    sel_max(a, ai, b, bi, mx, mxi);
    a = mn; ai = mni; b = mx; bi = mxi;
}

// fp32 -> (hi bf16, lo bf16) split, round-half-up on bit patterns (monotone, exact enough)
__device__ __forceinline__ void split1(float x, ushort& h, ushort& l) {
    unsigned u = __float_as_uint(x);
    unsigned hb = (u + 0x8000u) >> 16;
    float hf = __uint_as_float(hb << 16);
    float lo = x - hf;
    unsigned ul = __float_as_uint(lo);
    h = (ushort)hb;
    l = (ushort)((ul + 0x8000u) >> 16);
}

__device__ __forceinline__ void storeSplit(ushort* H, ushort* L, float4 v) {
    ushort4 h, l;
    split1(v.x, h.x, l.x);
    split1(v.y, h.y, l.y);
    split1(v.z, h.z, l.z);
    split1(v.w, h.w, l.w);
    *(ushort4*)H = h;
    *(ushort4*)L = l;
}

// ---------- kernel A: per-row sum of squares ----------
__global__ __launch_bounds__(256) void sumsq_kernel(const float* __restrict__ M,
                                                    float* __restrict__ sq) {
    const int row = blockIdx.x * 4 + (threadIdx.x >> 6);
    const int lane = threadIdx.x & 63;
    const float* p = M + (size_t)row * ND + lane * 8;
    float4 v0 = *(const float4*)p;
    float4 v1 = *(const float4*)(p + 4);
    float s = v0.x * v0.x + v0.y * v0.y + v0.z * v0.z + v0.w * v0.w
            + v1.x * v1.x + v1.y * v1.y + v1.z * v1.z + v1.w * v1.w;
#pragma unroll
    for (int off = 32; off >= 1; off >>= 1) s += __shfl_down(s, off, 64);
    if (lane == 0) sq[row] = s;
}

// ---------- kernel B: MFMA (bf16-split) Gram tile + fused per-row top-5 ----------
__global__ __launch_bounds__(256, 3) void dist_topk_kernel(const float* __restrict__ M,
                                                           const float* __restrict__ sq,
                                                           float* __restrict__ tvals,
                                                           int* __restrict__ tidx) {
    __shared__ ushort smem[(2 * BM + 2 * BN) * PAD]; // 51200 B
    ushort* Ah = smem;
    ushort* Al = smem + BM * PAD;
    ushort* Bh = smem + 2 * BM * PAD;
    ushort* Bl = smem + 2 * BM * PAD + BN * PAD;

    const int tid = threadIdx.x;
    const int lane = tid & 63;
    const int wid = tid >> 6;   // wave id = column quadrant (0..3)
    const int col = lane & 15;
    const int g = lane >> 4;
    const int i0 = blockIdx.x * BM;
    const int jb = blockIdx.y * JSPAN;

    const int lr = tid >> 3;        // 0..31 (staging row within 32-row group)
    const int lq = (tid & 7) * 4;   // 0,4,..,28 (k offset)

    f32x4 acc[4][4];
    const f32x4 zero = {0.f, 0.f, 0.f, 0.f};
#pragma unroll
    for (int m = 0; m < 4; ++m)
#pragma unroll
        for (int n = 0; n < 4; ++n) acc[m][n] = zero;

    for (int c = 0; c < ND / BK; ++c) {
        const int kc = c * BK;
        float4 va0 = *(const float4*)&M[(size_t)(i0 + lr) * ND + kc + lq];
        float4 va1 = *(const float4*)&M[(size_t)(i0 + 32 + lr) * ND + kc + lq];
        float4 vb[8];
#pragma unroll
        for (int p = 0; p < 8; ++p)
            vb[p] = *(const float4*)&M[(size_t)(jb + p * 32 + lr) * ND + kc + lq];
        __syncthreads();   // previous chunk's fragment reads complete
        storeSplit(&Ah[lr * PAD + lq], &Al[lr * PAD + lq], va0);
        storeSplit(&Ah[(32 + lr) * PAD + lq], &Al[(32 + lr) * PAD + lq], va1);
#pragma unroll
        for (int p = 0; p < 8; ++p)
            storeSplit(&Bh[(p * 32 + lr) * PAD + lq], &Bl[(p * 32 + lr) * PAD + lq], vb[p]);
        __syncthreads();

        bf16x8 ah[4], bh[4], t[4];
#pragma unroll
        for (int m = 0; m < 4; ++m)
            ah[m] = *(const bf16x8*)&Ah[(m * 16 + col) * PAD + g * 8];
#pragma unroll
        for (int n = 0; n < 4; ++n)
            bh[n] = *(const bf16x8*)&Bh[(wid * 64 + n * 16 + col) * PAD + g * 8];
#pragma unroll
        for (int m = 0; m < 4; ++m)
#pragma unroll
            for (int n = 0; n < 4; ++n)
                acc[m][n] = __builtin_amdgcn_mfma_f32_16x16x32_bf16(ah[m], bh[n], acc[m][n], 0, 0, 0);
#pragma unroll
        for (int n = 0; n < 4; ++n)
            t[n] = *(const bf16x8*)&Bl[(wid * 64 + n * 16 + col) * PAD + g * 8];
#pragma unroll
        for (int m = 0; m < 4; ++m)
#pragma unroll
            for (int n = 0; n < 4; ++n)
                acc[m][n] = __builtin_amdgcn_mfma_f32_16x16x32_bf16(ah[m], t[n], acc[m][n], 0, 0, 0);
#pragma unroll
        for (int m = 0; m < 4; ++m)
            ah[m] = *(const bf16x8*)&Al[(m * 16 + col) * PAD + g * 8];
#pragma unroll
        for (int m = 0; m < 4; ++m)
#pragma unroll
            for (int n = 0; n < 4; ++n)
                acc[m][n] = __builtin_amdgcn_mfma_f32_16x16x32_bf16(ah[m], bh[n], acc[m][n], 0, 0, 0);
    }

    __syncthreads();  // all fragment reads done; alias selection buffers over Ah/Al
    float* selv = (float*)smem;                           // [BM][4][KNB]
    int* seli = (int*)((char*)smem + BM * 4 * KNB * 4);   // [BM][4][KNB]

    float sqj[4]; int jg[4];
#pragma unroll
    for (int n = 0; n < 4; ++n) {
        jg[n] = jb + wid * 64 + n * 16 + col;
        sqj[n] = sq[jg[n]];
    }

#pragma unroll
    for (int m = 0; m < 4; ++m) {
#pragma unroll
        for (int r = 0; r < 4; ++r) {
            const int rloc = m * 16 + g * 4 + r;
            const int grow = i0 + rloc;
            // selection key: d2 - sq[i] = sq[j] - 2*dot (monotone per row)
            float v0 = fmaf(-2.f, acc[m][0][r], sqj[0]);
            float v1 = fmaf(-2.f, acc[m][1][r], sqj[1]);
            float v2 = fmaf(-2.f, acc[m][2][r], sqj[2]);
            float v3 = fmaf(-2.f, acc[m][3][r], sqj[3]);
            int j0 = jg[0], j1 = jg[1], j2 = jg[2], j3 = jg[3];
            if (j0 == grow) v0 = INFINITY;
            if (j1 == grow) v1 = INFINITY;
            if (j2 == grow) v2 = INFINITY;
            if (j3 == grow) v3 = INFINITY;
            cswap(v0, j0, v1, j1);
            cswap(v2, j2, v3, j3);
            cswap(v0, j0, v2, j2);
            cswap(v1, j1, v3, j3);
            cswap(v1, j1, v2, j2);
            float tv[5] = {v0, v1, v2, v3, INFINITY};
            int ti[5] = {j0, j1, j2, j3, 0};
#pragma unroll
            for (int msk = 1; msk <= 8; msk <<= 1) {
                float bv[5]; int bi2[5];
#pragma unroll
                for (int s = 0; s < 5; ++s) {
                    bv[s] = __shfl_xor(tv[s], msk, 64);
                    bi2[s] = __shfl_xor(ti[s], msk, 64);
                }
                merge5(tv, ti, bv, bi2);
            }
            if (col == 0) {
#pragma unroll
                for (int s = 0; s < 5; ++s) {
                    selv[rloc * (4 * KNB) + wid * KNB + s] = tv[s];
                    seli[rloc * (4 * KNB) + wid * KNB + s] = ti[s];
                }
            }
        }
    }
    __syncthreads();
    if (tid < BM) {
        float a[5]; int ai[5];
#pragma unroll
        for (int s = 0; s < 5; ++s) {
            a[s] = selv[tid * (4 * KNB) + s];
            ai[s] = seli[tid * (4 * KNB) + s];
        }
#pragma unroll
        for (int w = 1; w < 4; ++w) {
            float bv[5]; int bi2[5];
#pragma unroll
            for (int s = 0; s < 5; ++s) {
                bv[s] = selv[tid * (4 * KNB) + w * KNB + s];
                bi2[s] = seli[tid * (4 * KNB) + w * KNB + s];
            }
            merge5(a, ai, bv, bi2);
        }
        const size_t base = ((size_t)(i0 + tid) * NSPLIT + blockIdx.y) * KNB;
#pragma unroll
        for (int s = 0; s < 5; ++s) {
            tvals[base + s] = a[s];
            tidx[base + s] = ai[s];
        }
    }
}

// ---------- kernel C: merge splits, gather neighbors, std(ddof=1), MSE partial ----------
__global__ __launch_bounds__(256) void loss_kernel(const float* __restrict__ M,
                                                   const float* __restrict__ V1,
                                                   const float* __restrict__ tvals,
                                                   const int* __restrict__ tidx,
                                                   float* __restrict__ partial) {
    const int i = blockIdx.x;
    const int tid = threadIdx.x;
    __shared__ float svals[NSPLIT * KNB];
    __shared__ int sidx[NSPLIT * KNB];
    __shared__ int nb[KNB];
    __shared__ float wsum[4];
    if (tid < NSPLIT * KNB) {
        svals[tid] = tvals[(size_t)i * (NSPLIT * KNB) + tid];
        sidx[tid] = tidx[(size_t)i * (NSPLIT * KNB) + tid];
    }
    __syncthreads();
    if (tid == 0) {
        for (int s = 0; s < KNB; ++s) {
            float best = INFINITY; int bj = 0x7fffffff; int bpos = 0;
            for (int t = 0; t < NSPLIT * KNB; ++t) {
                float v = svals[t];
                int jj = sidx[t];
                if (v < best || (v == best && jj < bj)) { best = v; bj = jj; bpos = t; }
            }
            nb[s] = bj;
            svals[bpos] = INFINITY;
        }
    }
    __syncthreads();
    const int n0 = nb[0], n1 = nb[1], n2 = nb[2], n3 = nb[3], n4 = nb[4];
    float lsum = 0.f;
#pragma unroll
    for (int rep = 0; rep < ND / 256; ++rep) {
        const int d = rep * 256 + tid;
        float x0 = M[(size_t)n0 * ND + d];
        float x1 = M[(size_t)n1 * ND + d];
        float x2 = M[(size_t)n2 * ND + d];
        float x3 = M[(size_t)n3 * ND + d];
        float x4 = M[(size_t)n4 * ND + d];
        float mean = (x0 + x1 + x2 + x3 + x4) * 0.2f;
        float e0 = x0 - mean, e1 = x1 - mean, e2 = x2 - mean, e3 = x3 - mean, e4 = x4 - mean;
        float var = (e0 * e0 + e1 * e1 + e2 * e2 + e3 * e3 + e4 * e4) * 0.25f;
        float nstd = sqrtf(var);
        float pred = expf(0.5f * V1[(size_t)i * ND + d]);
        float df = pred - nstd;
        lsum = fmaf(df, df, lsum);
    }
#pragma unroll
    for (int off = 32; off >= 1; off >>= 1) lsum += __shfl_down(lsum, off, 64);
    if ((tid & 63) == 0) wsum[tid >> 6] = lsum;
    __syncthreads();
    if (tid == 0) partial[i] = (wsum[0] + wsum[1]) + (wsum[2] + wsum[3]);
}

// ---------- kernel D: deterministic final reduction ----------
__global__ __launch_bounds__(256) void finalize_kernel(const float* __restrict__ partial,
                                                       float* __restrict__ out) {
    const int tid = threadIdx.x;
    double s = 0.0;
    for (int i = tid; i < NB; i += 256) s += (double)partial[i];
#pragma unroll
    for (int off = 32; off >= 1; off >>= 1) s += __shfl_down(s, off, 64);
    __shared__ double dsum[4];
    if ((tid & 63) == 0) dsum[tid >> 6] = s;
    __syncthreads();
    if (tid == 0)
        out[0] = (float)(((dsum[0] + dsum[1]) + (dsum[2] + dsum[3])) / ((double)NB * (double)ND));
}

extern "C" void kernel_launch(void* const* d_in, const int* in_sizes, int n_in,
                              void* d_out, int out_size, void* d_ws, size_t ws_size,
                              hipStream_t stream) {
    const float* mean1 = (const float*)d_in[0];
    const float* var1 = (const float*)d_in[1];

    float* ws = (float*)d_ws;
    float* sq = ws;                                               // NB floats
    float* tvals = ws + NB;                                       // NB*NSPLIT*KNB floats
    int* tidx = (int*)(tvals + (size_t)NB * NSPLIT * KNB);        // NB*NSPLIT*KNB ints
    float* partial = (float*)(tidx + (size_t)NB * NSPLIT * KNB);  // NB floats
    float* out = (float*)d_out;

    sumsq_kernel<<<NB / 4, 256, 0, stream>>>(mean1, sq);
    dist_topk_kernel<<<dim3(NB / BM, NSPLIT), 256, 0, stream>>>(mean1, sq, tvals, tidx);
    loss_kernel<<<NB, 256, 0, stream>>>(mean1, var1, tvals, tidx, partial);
    finalize_kernel<<<1, 256, 0, stream>>>(partial, out);
}

// Round 3
// 158.848 us; speedup vs baseline: 2.3578x; 1.2961x over previous
//
#include <hip/hip_runtime.h>
#include <math.h>

#define NB 4096
#define ND 512
#define BT 256      /* BM = BN = 256 */
#define BK 32
#define NSPLIT 16   /* NB / BT */
#define KNB 5
#define CHUNKS (ND / BK) /* 16 */
#define LDSBUF 65536

typedef float f32x4 __attribute__((ext_vector_type(4)));
typedef short bf16x8 __attribute__((ext_vector_type(8)));
typedef unsigned short u16x8 __attribute__((ext_vector_type(8)));

// ---------- helpers: (value,index) predicated min/max ----------
__device__ __forceinline__ void sel_min(float av, int ai, float bv, int bi, float& ov, int& oi) {
    bool p = av <= bv;
    ov = p ? av : bv;
    oi = p ? ai : bi;
}
__device__ __forceinline__ void sel_max(float av, int ai, float bv, int bi, float& ov, int& oi) {
    bool p = av >= bv;
    ov = p ? av : bv;
    oi = p ? ai : bi;
}

// Merge two sorted-ascending 5-lists, keep 5 smallest (static network).
__device__ __forceinline__ void merge5(float (&a)[5], int (&ai)[5],
                                       const float (&b)[5], const int (&bi)[5]) {
    float c[5]; int ci[5];
    float m; int mi;
    sel_min(a[0], ai[0], b[0], bi[0], c[0], ci[0]);
    sel_max(a[0], ai[0], b[0], bi[0], m, mi);
    sel_min(a[1], ai[1], m, mi, c[1], ci[1]);
    sel_min(c[1], ci[1], b[1], bi[1], c[1], ci[1]);
    sel_max(a[1], ai[1], b[0], bi[0], m, mi);
    sel_min(a[2], ai[2], m, mi, c[2], ci[2]);
    sel_max(a[0], ai[0], b[1], bi[1], m, mi);
    sel_min(c[2], ci[2], m, mi, c[2], ci[2]);
    sel_min(c[2], ci[2], b[2], bi[2], c[2], ci[2]);
    sel_max(a[2], ai[2], b[0], bi[0], m, mi);
    sel_min(a[3], ai[3], m, mi, c[3], ci[3]);
    sel_max(a[1], ai[1], b[1], bi[1], m, mi);
    sel_min(c[3], ci[3], m, mi, c[3], ci[3]);
    sel_max(a[0], ai[0], b[2], bi[2], m, mi);
    sel_min(c[3], ci[3], m, mi, c[3], ci[3]);
    sel_min(c[3], ci[3], b[3], bi[3], c[3], ci[3]);
    sel_max(a[3], ai[3], b[0], bi[0], m, mi);
    sel_min(a[4], ai[4], m, mi, c[4], ci[4]);
    sel_max(a[2], ai[2], b[1], bi[1], m, mi);
    sel_min(c[4], ci[4], m, mi, c[4], ci[4]);
    sel_max(a[1], ai[1], b[2], bi[2], m, mi);
    sel_min(c[4], ci[4], m, mi, c[4], ci[4]);
    sel_max(a[0], ai[0], b[3], bi[3], m, mi);
    sel_min(c[4], ci[4], m, mi, c[4], ci[4]);
    sel_min(c[4], ci[4], b[4], bi[4], c[4], ci[4]);
#pragma unroll
    for (int s = 0; s < 5; ++s) { a[s] = c[s]; ai[s] = ci[s]; }
}

__device__ __forceinline__ void cswap(float& a, int& ai, float& b, int& bi) {
    float mn, mx; int mni, mxi;
    sel_min(a, ai, b, bi, mn, mni);
    sel_max(a, ai, b, bi, mx, mxi);
    a = mn; ai = mni; b = mx; bi = mxi;
}

// fp32 -> (hi bf16, lo bf16) split, round-half-up on bit patterns
__device__ __forceinline__ void split1(float x, unsigned short& h, unsigned short& l) {
    unsigned u = __float_as_uint(x);
    unsigned hb = (u + 0x8000u) >> 16;
    float hf = __uint_as_float(hb << 16);
    float lo = x - hf;
    unsigned ul = __float_as_uint(lo);
    h = (unsigned short)hb;
    l = (unsigned short)((ul + 0x8000u) >> 16);
}

// ---------- kernel A: global fp32 -> (Mh, Ml) bf16 split + row sumsq ----------
__global__ __launch_bounds__(256) void split_sumsq_kernel(const float* __restrict__ M,
                                                          unsigned short* __restrict__ Mh,
                                                          unsigned short* __restrict__ Ml,
                                                          float* __restrict__ sq) {
    const int row = blockIdx.x * 4 + (threadIdx.x >> 6);
    const int lane = threadIdx.x & 63;
    const float* p = M + (size_t)row * ND + lane * 8;
    float4 v0 = *(const float4*)p;
    float4 v1 = *(const float4*)(p + 4);
    u16x8 h, l;
    split1(v0.x, ((unsigned short*)&h)[0], ((unsigned short*)&l)[0]);
    split1(v0.y, ((unsigned short*)&h)[1], ((unsigned short*)&l)[1]);
    split1(v0.z, ((unsigned short*)&h)[2], ((unsigned short*)&l)[2]);
    split1(v0.w, ((unsigned short*)&h)[3], ((unsigned short*)&l)[3]);
    split1(v1.x, ((unsigned short*)&h)[4], ((unsigned short*)&l)[4]);
    split1(v1.y, ((unsigned short*)&h)[5], ((unsigned short*)&l)[5]);
    split1(v1.z, ((unsigned short*)&h)[6], ((unsigned short*)&l)[6]);
    split1(v1.w, ((unsigned short*)&h)[7], ((unsigned short*)&l)[7]);
    *(u16x8*)&Mh[(size_t)row * ND + lane * 8] = h;
    *(u16x8*)&Ml[(size_t)row * ND + lane * 8] = l;
    float s = v0.x * v0.x + v0.y * v0.y + v0.z * v0.z + v0.w * v0.w
            + v1.x * v1.x + v1.y * v1.y + v1.z * v1.z + v1.w * v1.w;
#pragma unroll
    for (int off = 32; off >= 1; off >>= 1) s += __shfl_down(s, off, 64);
    if (lane == 0) sq[row] = s;
}

// ---------- staging: 8 global_load_lds units per wave, source-swizzled ----------
__device__ __forceinline__ void stage_chunk(const unsigned short* __restrict__ Mh,
                                            const unsigned short* __restrict__ Ml,
                                            char* smem, int buf, int kc,
                                            int i0, int jb, int wid, int lane) {
#pragma unroll
    for (int s2 = 0; s2 < 8; ++s2) {
        const int u = wid * 8 + s2;
        const int sub = u >> 4;            // 0:Ah 1:Al 2:Bh 3:Bl
        const int rb = (u & 15) * 16;
        const int rl = rb + (lane >> 2);   // tile-local row 0..255
        const int gg = (lane & 3) ^ ((rl >> 1) & 3);  // swizzled 16B slot
        const unsigned short* srcm = (sub & 1) ? Ml : Mh;
        const int grow = ((sub < 2) ? i0 : jb) + rl;
        const unsigned short* src = srcm + (size_t)grow * ND + kc + gg * 8;
        char* dst = smem + buf * LDSBUF + sub * 16384 + (u & 15) * 1024;
        __builtin_amdgcn_global_load_lds(
            (const __attribute__((address_space(1))) void*)src,
            (__attribute__((address_space(3))) void*)dst, 16, 0, 0);
    }
}

// ---------- kernel B: MFMA (bf16 3-pass) Gram tile + fused per-row top-5 ----------
__global__ __launch_bounds__(512, 2) void dist_topk_kernel(const unsigned short* __restrict__ Mh,
                                                           const unsigned short* __restrict__ Ml,
                                                           const float* __restrict__ sq,
                                                           float* __restrict__ tvals,
                                                           int* __restrict__ tidx) {
    extern __shared__ char smem[];
    const int tid = threadIdx.x;
    const int lane = tid & 63;
    const int wid = tid >> 6;       // 0..7
    const int wr = wid >> 1;        // wave-row 0..3 (rows wr*64)
    const int wc = wid & 1;         // wave-col 0..1 (cols wc*128)
    const int col16 = lane & 15;
    const int g = lane >> 4;        // k-group 0..3
    const int i0 = blockIdx.x * BT;
    const int jb = blockIdx.y * BT;

    f32x4 acc[4][8];
    const f32x4 zero = {0.f, 0.f, 0.f, 0.f};
#pragma unroll
    for (int m = 0; m < 4; ++m)
#pragma unroll
        for (int n = 0; n < 8; ++n) acc[m][n] = zero;

    stage_chunk(Mh, Ml, smem, 0, 0, i0, jb, wid, lane);

    for (int c = 0; c < CHUNKS; ++c) {
        const int cur = c & 1;
        __syncthreads();  // drains stage(c) (vmcnt 0) + protects prev-buffer reads
        if (c + 1 < CHUNKS)
            stage_chunk(Mh, Ml, smem, cur ^ 1, (c + 1) * BK, i0, jb, wid, lane);

        const char* bp = smem + cur * LDSBUF;
        bf16x8 ah[4], al[4], bh[8], bl[8];
#pragma unroll
        for (int m = 0; m < 4; ++m) {
            const int r = wr * 64 + m * 16 + col16;
            ah[m] = *(const bf16x8*)(bp + r * 64 + ((g ^ ((r >> 1) & 3)) << 4));
        }
#pragma unroll
        for (int n = 0; n < 8; ++n) {
            const int r = wc * 128 + n * 16 + col16;
            bh[n] = *(const bf16x8*)(bp + 32768 + r * 64 + ((g ^ ((r >> 1) & 3)) << 4));
        }
#pragma unroll
        for (int m = 0; m < 4; ++m)
#pragma unroll
            for (int n = 0; n < 8; ++n)
                acc[m][n] = __builtin_amdgcn_mfma_f32_16x16x32_bf16(ah[m], bh[n], acc[m][n], 0, 0, 0);
#pragma unroll
        for (int m = 0; m < 4; ++m) {
            const int r = wr * 64 + m * 16 + col16;
            al[m] = *(const bf16x8*)(bp + 16384 + r * 64 + ((g ^ ((r >> 1) & 3)) << 4));
        }
#pragma unroll
        for (int m = 0; m < 4; ++m)
#pragma unroll
            for (int n = 0; n < 8; ++n)
                acc[m][n] = __builtin_amdgcn_mfma_f32_16x16x32_bf16(al[m], bh[n], acc[m][n], 0, 0, 0);
#pragma unroll
        for (int n = 0; n < 8; ++n) {
            const int r = wc * 128 + n * 16 + col16;
            bl[n] = *(const bf16x8*)(bp + 49152 + r * 64 + ((g ^ ((r >> 1) & 3)) << 4));
        }
#pragma unroll
        for (int m = 0; m < 4; ++m)
#pragma unroll
            for (int n = 0; n < 8; ++n)
                acc[m][n] = __builtin_amdgcn_mfma_f32_16x16x32_bf16(ah[m], bl[n], acc[m][n], 0, 0, 0);
    }

    __syncthreads();  // all LDS reads done; alias selection buffers
    float* selv = (float*)smem;                 // [256][2][5]
    int* seli = (int*)(smem + 256 * 2 * 5 * 4); // [256][2][5]

    float sqj[8]; int jgv[8];
#pragma unroll
    for (int n = 0; n < 8; ++n) {
        jgv[n] = jb + wc * 128 + n * 16 + col16;
        sqj[n] = sq[jgv[n]];
    }

#pragma unroll
    for (int m = 0; m < 4; ++m) {
#pragma unroll
        for (int r = 0; r < 4; ++r) {
            const int rloc = wr * 64 + m * 16 + g * 4 + r;
            const int grow = i0 + rloc;
            float v[8]; int j[8];
#pragma unroll
            for (int n = 0; n < 8; ++n) {
                v[n] = fmaf(-2.f, acc[m][n][r], sqj[n]);  // key = sq[j] - 2*dot
                j[n] = jgv[n];
                if (j[n] == grow) v[n] = INFINITY;        // mask diagonal
            }
            // sort v0..3 and v4..7 (4-nets), then merge into top-5 of 8
            cswap(v[0], j[0], v[1], j[1]); cswap(v[2], j[2], v[3], j[3]);
            cswap(v[0], j[0], v[2], j[2]); cswap(v[1], j[1], v[3], j[3]);
            cswap(v[1], j[1], v[2], j[2]);
            cswap(v[4], j[4], v[5], j[5]); cswap(v[6], j[6], v[7], j[7]);
            cswap(v[4], j[4], v[6], j[6]); cswap(v[5], j[5], v[7], j[7]);
            cswap(v[5], j[5], v[6], j[6]);
            float tv[5] = {v[0], v[1], v[2], v[3], INFINITY};
            int ti[5] = {j[0], j[1], j[2], j[3], 0};
            float bv[5] = {v[4], v[5], v[6], v[7], INFINITY};
            int bi2[5] = {j[4], j[5], j[6], j[7], 0};
            merge5(tv, ti, bv, bi2);
            // butterfly across the 16 lanes sharing this row
#pragma unroll
            for (int msk = 1; msk <= 8; msk <<= 1) {
                float xv[5]; int xi[5];
#pragma unroll
                for (int s = 0; s < 5; ++s) {
                    xv[s] = __shfl_xor(tv[s], msk, 64);
                    xi[s] = __shfl_xor(ti[s], msk, 64);
                }
                merge5(tv, ti, xv, xi);
            }
            if (col16 == 0) {
#pragma unroll
                for (int s = 0; s < 5; ++s) {
                    selv[(rloc * 2 + wc) * 5 + s] = tv[s];
                    seli[(rloc * 2 + wc) * 5 + s] = ti[s];
                }
            }
        }
    }
    __syncthreads();
    if (tid < BT) {
        float a[5]; int ai[5];
        float b[5]; int bi2[5];
#pragma unroll
        for (int s = 0; s < 5; ++s) {
            a[s] = selv[(tid * 2 + 0) * 5 + s];
            ai[s] = seli[(tid * 2 + 0) * 5 + s];
            b[s] = selv[(tid * 2 + 1) * 5 + s];
            bi2[s] = seli[(tid * 2 + 1) * 5 + s];
        }
        merge5(a, ai, b, bi2);
        const size_t base = ((size_t)(i0 + tid) * NSPLIT + blockIdx.y) * KNB;
#pragma unroll
        for (int s = 0; s < 5; ++s) {
            tvals[base + s] = a[s];
            tidx[base + s] = ai[s];
        }
    }
}

// ---------- kernel C: merge splits, gather neighbors, std(ddof=1), MSE partial ----------
__global__ __launch_bounds__(256) void loss_kernel(const float* __restrict__ M,
                                                   const float* __restrict__ V1,
                                                   const float* __restrict__ tvals,
                                                   const int* __restrict__ tidx,
                                                   float* __restrict__ partial) {
    const int i = blockIdx.x;
    const int tid = threadIdx.x;
    __shared__ float svals[NSPLIT * KNB];
    __shared__ int sidx[NSPLIT * KNB];
    __shared__ int nb[KNB];
    __shared__ float wsum[4];
    if (tid < NSPLIT * KNB) {
        svals[tid] = tvals[(size_t)i * (NSPLIT * KNB) + tid];
        sidx[tid] = tidx[(size_t)i * (NSPLIT * KNB) + tid];
    }
    __syncthreads();
    if (tid == 0) {
        for (int s = 0; s < KNB; ++s) {
            float best = INFINITY; int bj = 0x7fffffff; int bpos = 0;
            for (int t = 0; t < NSPLIT * KNB; ++t) {
                float v = svals[t];
                int jj = sidx[t];
                if (v < best || (v == best && jj < bj)) { best = v; bj = jj; bpos = t; }
            }
            nb[s] = bj;
            svals[bpos] = INFINITY;
        }
    }
    __syncthreads();
    const int n0 = nb[0], n1 = nb[1], n2 = nb[2], n3 = nb[3], n4 = nb[4];
    float lsum = 0.f;
#pragma unroll
    for (int rep = 0; rep < ND / 256; ++rep) {
        const int d = rep * 256 + tid;
        float x0 = M[(size_t)n0 * ND + d];
        float x1 = M[(size_t)n1 * ND + d];
        float x2 = M[(size_t)n2 * ND + d];
        float x3 = M[(size_t)n3 * ND + d];
        float x4 = M[(size_t)n4 * ND + d];
        float mean = (x0 + x1 + x2 + x3 + x4) * 0.2f;
        float e0 = x0 - mean, e1 = x1 - mean, e2 = x2 - mean, e3 = x3 - mean, e4 = x4 - mean;
        float var = (e0 * e0 + e1 * e1 + e2 * e2 + e3 * e3 + e4 * e4) * 0.25f;
        float nstd = sqrtf(var);
        float pred = expf(0.5f * V1[(size_t)i * ND + d]);
        float df = pred - nstd;
        lsum = fmaf(df, df, lsum);
    }
#pragma unroll
    for (int off = 32; off >= 1; off >>= 1) lsum += __shfl_down(lsum, off, 64);
    if ((tid & 63) == 0) wsum[tid >> 6] = lsum;
    __syncthreads();
    if (tid == 0) partial[i] = (wsum[0] + wsum[1]) + (wsum[2] + wsum[3]);
}

// ---------- kernel D: deterministic final reduction ----------
__global__ __launch_bounds__(256) void finalize_kernel(const float* __restrict__ partial,
                                                       float* __restrict__ out) {
    const int tid = threadIdx.x;
    double s = 0.0;
    for (int i = tid; i < NB; i += 256) s += (double)partial[i];
#pragma unroll
    for (int off = 32; off >= 1; off >>= 1) s += __shfl_down(s, off, 64);
    __shared__ double dsum[4];
    if ((tid & 63) == 0) dsum[tid >> 6] = s;
    __syncthreads();
    if (tid == 0)
        out[0] = (float)(((dsum[0] + dsum[1]) + (dsum[2] + dsum[3])) / ((double)NB * (double)ND));
}

extern "C" void kernel_launch(void* const* d_in, const int* in_sizes, int n_in,
                              void* d_out, int out_size, void* d_ws, size_t ws_size,
                              hipStream_t stream) {
    const float* mean1 = (const float*)d_in[0];
    const float* var1 = (const float*)d_in[1];

    char* ws = (char*)d_ws;
    unsigned short* Mh = (unsigned short*)ws;                       // 4 MB
    unsigned short* Ml = (unsigned short*)(ws + (size_t)NB * ND * 2);          // 4 MB
    float* sq = (float*)(ws + (size_t)NB * ND * 4);                            // 16 KB
    float* tvals = (float*)(ws + (size_t)NB * ND * 4 + NB * 4);                // 1.31 MB
    int* tidx = (int*)(ws + (size_t)NB * ND * 4 + NB * 4 + (size_t)NB * NSPLIT * KNB * 4);
    float* partial = (float*)(ws + (size_t)NB * ND * 4 + NB * 4 + (size_t)NB * NSPLIT * KNB * 8);
    float* out = (float*)d_out;

    // allow 128 KiB dynamic LDS (idempotent; not a stream op, capture-safe)
    (void)hipFuncSetAttribute((const void*)dist_topk_kernel,
                              hipFuncAttributeMaxDynamicSharedMemorySize, 2 * LDSBUF);

    split_sumsq_kernel<<<NB / 4, 256, 0, stream>>>(mean1, Mh, Ml, sq);
    dist_topk_kernel<<<dim3(NB / BT, NB / BT), 512, 2 * LDSBUF, stream>>>(Mh, Ml, sq, tvals, tidx);
    loss_kernel<<<NB, 256, 0, stream>>>(mean1, var1, tvals, tidx, partial);
    finalize_kernel<<<1, 256, 0, stream>>>(partial, out);
}

// Round 4
// 92.209 us; speedup vs baseline: 4.0617x; 1.7227x over previous
//
#include <hip/hip_runtime.h>
#include <math.h>

#define NB 4096
#define ND 512
#define BT 256      /* BM = BN = 256 */
#define BK 32
#define NSPLIT 16   /* NB / BT */
#define KNB 5
#define CHUNKS (ND / BK) /* 16 */
#define LDSBUF 65536

typedef float f32x4 __attribute__((ext_vector_type(4)));
typedef short bf16x8 __attribute__((ext_vector_type(8)));
typedef unsigned short u16x8 __attribute__((ext_vector_type(8)));

// ---------- helpers: (value,index) predicated min/max ----------
__device__ __forceinline__ void sel_min(float av, int ai, float bv, int bi, float& ov, int& oi) {
    bool p = av <= bv;
    ov = p ? av : bv;
    oi = p ? ai : bi;
}
__device__ __forceinline__ void sel_max(float av, int ai, float bv, int bi, float& ov, int& oi) {
    bool p = av >= bv;
    ov = p ? av : bv;
    oi = p ? ai : bi;
}

// Merge two sorted-ascending 5-lists, keep 5 smallest (static network).
__device__ __forceinline__ void merge5(float (&a)[5], int (&ai)[5],
                                       const float (&b)[5], const int (&bi)[5]) {
    float c[5]; int ci[5];
    float m; int mi;
    sel_min(a[0], ai[0], b[0], bi[0], c[0], ci[0]);
    sel_max(a[0], ai[0], b[0], bi[0], m, mi);
    sel_min(a[1], ai[1], m, mi, c[1], ci[1]);
    sel_min(c[1], ci[1], b[1], bi[1], c[1], ci[1]);
    sel_max(a[1], ai[1], b[0], bi[0], m, mi);
    sel_min(a[2], ai[2], m, mi, c[2], ci[2]);
    sel_max(a[0], ai[0], b[1], bi[1], m, mi);
    sel_min(c[2], ci[2], m, mi, c[2], ci[2]);
    sel_min(c[2], ci[2], b[2], bi[2], c[2], ci[2]);
    sel_max(a[2], ai[2], b[0], bi[0], m, mi);
    sel_min(a[3], ai[3], m, mi, c[3], ci[3]);
    sel_max(a[1], ai[1], b[1], bi[1], m, mi);
    sel_min(c[3], ci[3], m, mi, c[3], ci[3]);
    sel_max(a[0], ai[0], b[2], bi[2], m, mi);
    sel_min(c[3], ci[3], m, mi, c[3], ci[3]);
    sel_min(c[3], ci[3], b[3], bi[3], c[3], ci[3]);
    sel_max(a[3], ai[3], b[0], bi[0], m, mi);
    sel_min(a[4], ai[4], m, mi, c[4], ci[4]);
    sel_max(a[2], ai[2], b[1], bi[1], m, mi);
    sel_min(c[4], ci[4], m, mi, c[4], ci[4]);
    sel_max(a[1], ai[1], b[2], bi[2], m, mi);
    sel_min(c[4], ci[4], m, mi, c[4], ci[4]);
    sel_max(a[0], ai[0], b[3], bi[3], m, mi);
    sel_min(c[4], ci[4], m, mi, c[4], ci[4]);
    sel_min(c[4], ci[4], b[4], bi[4], c[4], ci[4]);
#pragma unroll
    for (int s = 0; s < 5; ++s) { a[s] = c[s]; ai[s] = ci[s]; }
}

__device__ __forceinline__ void cswap(float& a, int& ai, float& b, int& bi) {
    float mn, mx; int mni, mxi;
    sel_min(a, ai, b, bi, mn, mni);
    sel_max(a, ai, b, bi, mx, mxi);
    a = mn; ai = mni; b = mx; bi = mxi;
}

// fp32 -> (hi bf16, lo bf16) split, round-half-up on bit patterns
__device__ __forceinline__ void split1(float x, unsigned short& h, unsigned short& l) {
    unsigned u = __float_as_uint(x);
    unsigned hb = (u + 0x8000u) >> 16;
    float hf = __uint_as_float(hb << 16);
    float lo = x - hf;
    unsigned ul = __float_as_uint(lo);
    h = (unsigned short)hb;
    l = (unsigned short)((ul + 0x8000u) >> 16);
}

// ---------- kernel A: global fp32 -> (Mh, Ml) bf16 split + row sumsq ----------
__global__ __launch_bounds__(256) void split_sumsq_kernel(const float* __restrict__ M,
                                                          unsigned short* __restrict__ Mh,
                                                          unsigned short* __restrict__ Ml,
                                                          float* __restrict__ sq) {
    const int row = blockIdx.x * 4 + (threadIdx.x >> 6);
    const int lane = threadIdx.x & 63;
    const float* p = M + (size_t)row * ND + lane * 8;
    float4 v0 = *(const float4*)p;
    float4 v1 = *(const float4*)(p + 4);
    u16x8 h, l;
    split1(v0.x, ((unsigned short*)&h)[0], ((unsigned short*)&l)[0]);
    split1(v0.y, ((unsigned short*)&h)[1], ((unsigned short*)&l)[1]);
    split1(v0.z, ((unsigned short*)&h)[2], ((unsigned short*)&l)[2]);
    split1(v0.w, ((unsigned short*)&h)[3], ((unsigned short*)&l)[3]);
    split1(v1.x, ((unsigned short*)&h)[4], ((unsigned short*)&l)[4]);
    split1(v1.y, ((unsigned short*)&h)[5], ((unsigned short*)&l)[5]);
    split1(v1.z, ((unsigned short*)&h)[6], ((unsigned short*)&l)[6]);
    split1(v1.w, ((unsigned short*)&h)[7], ((unsigned short*)&l)[7]);
    *(u16x8*)&Mh[(size_t)row * ND + lane * 8] = h;
    *(u16x8*)&Ml[(size_t)row * ND + lane * 8] = l;
    float s = v0.x * v0.x + v0.y * v0.y + v0.z * v0.z + v0.w * v0.w
            + v1.x * v1.x + v1.y * v1.y + v1.z * v1.z + v1.w * v1.w;
#pragma unroll
    for (int off = 32; off >= 1; off >>= 1) s += __shfl_down(s, off, 64);
    if (lane == 0) sq[row] = s;
}

// ---------- staging: 8 global_load_lds units per wave, source-swizzled ----------
__device__ __forceinline__ void stage_chunk(const unsigned short* __restrict__ Mh,
                                            const unsigned short* __restrict__ Ml,
                                            char* smem, int buf, int kc,
                                            int i0, int jb, int wid, int lane) {
#pragma unroll
    for (int s2 = 0; s2 < 8; ++s2) {
        const int u = wid * 8 + s2;
        const int sub = u >> 4;            // 0:Ah 1:Al 2:Bh 3:Bl
        const int rb = (u & 15) * 16;
        const int rl = rb + (lane >> 2);   // tile-local row 0..255
        const int gg = (lane & 3) ^ ((rl >> 1) & 3);  // swizzled 16B slot
        const unsigned short* srcm = (sub & 1) ? Ml : Mh;
        const int grow = ((sub < 2) ? i0 : jb) + rl;
        const unsigned short* src = srcm + (size_t)grow * ND + kc + gg * 8;
        char* dst = smem + buf * LDSBUF + sub * 16384 + (u & 15) * 1024;
        __builtin_amdgcn_global_load_lds(
            (const __attribute__((address_space(1))) void*)src,
            (__attribute__((address_space(3))) void*)dst, 16, 0, 0);
    }
}

// ---------- kernel B: MFMA (bf16 3-pass) Gram tile + fused per-row top-5 ----------
__global__ __launch_bounds__(512, 2) void dist_topk_kernel(const unsigned short* __restrict__ Mh,
                                                           const unsigned short* __restrict__ Ml,
                                                           const float* __restrict__ sq,
                                                           float* __restrict__ tvals,
                                                           int* __restrict__ tidx) {
    extern __shared__ char smem[];
    const int tid = threadIdx.x;
    const int lane = tid & 63;
    const int wid = tid >> 6;       // 0..7
    const int wr = wid >> 1;        // wave-row 0..3 (rows wr*64)
    const int wc = wid & 1;         // wave-col 0..1 (cols wc*128)
    const int col16 = lane & 15;
    const int g = lane >> 4;        // k-group 0..3
    const int i0 = blockIdx.x * BT;
    const int jb = blockIdx.y * BT;

    f32x4 acc[4][8];
    const f32x4 zero = {0.f, 0.f, 0.f, 0.f};
#pragma unroll
    for (int m = 0; m < 4; ++m)
#pragma unroll
        for (int n = 0; n < 8; ++n) acc[m][n] = zero;

    stage_chunk(Mh, Ml, smem, 0, 0, i0, jb, wid, lane);

    for (int c = 0; c < CHUNKS; ++c) {
        const int cur = c & 1;
        __syncthreads();  // drains stage(c) (vmcnt 0) + protects prev-buffer reads
        if (c + 1 < CHUNKS)
            stage_chunk(Mh, Ml, smem, cur ^ 1, (c + 1) * BK, i0, jb, wid, lane);

        const char* bp = smem + cur * LDSBUF;
        bf16x8 ah[4], al[4], bh[8], bl[8];
#pragma unroll
        for (int m = 0; m < 4; ++m) {
            const int r = wr * 64 + m * 16 + col16;
            ah[m] = *(const bf16x8*)(bp + r * 64 + ((g ^ ((r >> 1) & 3)) << 4));
        }
#pragma unroll
        for (int n = 0; n < 8; ++n) {
            const int r = wc * 128 + n * 16 + col16;
            bh[n] = *(const bf16x8*)(bp + 32768 + r * 64 + ((g ^ ((r >> 1) & 3)) << 4));
        }
#pragma unroll
        for (int m = 0; m < 4; ++m)
#pragma unroll
            for (int n = 0; n < 8; ++n)
                acc[m][n] = __builtin_amdgcn_mfma_f32_16x16x32_bf16(ah[m], bh[n], acc[m][n], 0, 0, 0);
#pragma unroll
        for (int m = 0; m < 4; ++m) {
            const int r = wr * 64 + m * 16 + col16;
            al[m] = *(const bf16x8*)(bp + 16384 + r * 64 + ((g ^ ((r >> 1) & 3)) << 4));
        }
#pragma unroll
        for (int m = 0; m < 4; ++m)
#pragma unroll
            for (int n = 0; n < 8; ++n)
                acc[m][n] = __builtin_amdgcn_mfma_f32_16x16x32_bf16(al[m], bh[n], acc[m][n], 0, 0, 0);
#pragma unroll
        for (int n = 0; n < 8; ++n) {
            const int r = wc * 128 + n * 16 + col16;
            bl[n] = *(const bf16x8*)(bp + 49152 + r * 64 + ((g ^ ((r >> 1) & 3)) << 4));
        }
#pragma unroll
        for (int m = 0; m < 4; ++m)
#pragma unroll
            for (int n = 0; n < 8; ++n)
                acc[m][n] = __builtin_amdgcn_mfma_f32_16x16x32_bf16(ah[m], bl[n], acc[m][n], 0, 0, 0);
    }

    __syncthreads();  // all LDS reads done; alias selection buffers
    float* selv = (float*)smem;                 // [256][2][5]
    int* seli = (int*)(smem + 256 * 2 * 5 * 4); // [256][2][5]

    float sqj[8]; int jgv[8];
#pragma unroll
    for (int n = 0; n < 8; ++n) {
        jgv[n] = jb + wc * 128 + n * 16 + col16;
        sqj[n] = sq[jgv[n]];
    }

#pragma unroll
    for (int m = 0; m < 4; ++m) {
#pragma unroll
        for (int r = 0; r < 4; ++r) {
            const int rloc = wr * 64 + m * 16 + g * 4 + r;
            const int grow = i0 + rloc;
            float v[8]; int j[8];
#pragma unroll
            for (int n = 0; n < 8; ++n) {
                v[n] = fmaf(-2.f, acc[m][n][r], sqj[n]);  // key = sq[j] - 2*dot
                j[n] = jgv[n];
                if (j[n] == grow) v[n] = INFINITY;        // mask diagonal
            }
            // sort v0..3 and v4..7 (4-nets), then merge into top-5 of 8
            cswap(v[0], j[0], v[1], j[1]); cswap(v[2], j[2], v[3], j[3]);
            cswap(v[0], j[0], v[2], j[2]); cswap(v[1], j[1], v[3], j[3]);
            cswap(v[1], j[1], v[2], j[2]);
            cswap(v[4], j[4], v[5], j[5]); cswap(v[6], j[6], v[7], j[7]);
            cswap(v[4], j[4], v[6], j[6]); cswap(v[5], j[5], v[7], j[7]);
            cswap(v[5], j[5], v[6], j[6]);
            float tv[5] = {v[0], v[1], v[2], v[3], INFINITY};
            int ti[5] = {j[0], j[1], j[2], j[3], 0};
            float bv[5] = {v[4], v[5], v[6], v[7], INFINITY};
            int bi2[5] = {j[4], j[5], j[6], j[7], 0};
            merge5(tv, ti, bv, bi2);
            // butterfly across the 16 lanes sharing this row
#pragma unroll
            for (int msk = 1; msk <= 8; msk <<= 1) {
                float xv[5]; int xi[5];
#pragma unroll
                for (int s = 0; s < 5; ++s) {
                    xv[s] = __shfl_xor(tv[s], msk, 64);
                    xi[s] = __shfl_xor(ti[s], msk, 64);
                }
                merge5(tv, ti, xv, xi);
            }
            if (col16 == 0) {
#pragma unroll
                for (int s = 0; s < 5; ++s) {
                    selv[(rloc * 2 + wc) * 5 + s] = tv[s];
                    seli[(rloc * 2 + wc) * 5 + s] = ti[s];
                }
            }
        }
    }
    __syncthreads();
    if (tid < BT) {
        float a[5]; int ai[5];
        float b[5]; int bi2[5];
#pragma unroll
        for (int s = 0; s < 5; ++s) {
            a[s] = selv[(tid * 2 + 0) * 5 + s];
            ai[s] = seli[(tid * 2 + 0) * 5 + s];
            b[s] = selv[(tid * 2 + 1) * 5 + s];
            bi2[s] = seli[(tid * 2 + 1) * 5 + s];
        }
        merge5(a, ai, b, bi2);
        const size_t base = ((size_t)(i0 + tid) * NSPLIT + blockIdx.y) * KNB;
#pragma unroll
        for (int s = 0; s < 5; ++s) {
            tvals[base + s] = a[s];
            tidx[base + s] = ai[s];
        }
    }
}

// ---------- kernel C: one wave per row — parallel 16-list merge + std(ddof=1) + MSE ----------
__global__ __launch_bounds__(256) void loss_kernel(const float* __restrict__ M,
                                                   const float* __restrict__ V1,
                                                   const float* __restrict__ tvals,
                                                   const int* __restrict__ tidx,
                                                   float* __restrict__ partial) {
    const int row = blockIdx.x * 4 + (threadIdx.x >> 6);
    const int lane = threadIdx.x & 63;

    // lanes 0..15: one sorted 5-list each; lanes 16..63: +INF lists
    float a[5]; int ai[5];
    if (lane < NSPLIT) {
        const size_t base = (size_t)row * (NSPLIT * KNB) + lane * KNB;
#pragma unroll
        for (int s = 0; s < 5; ++s) { a[s] = tvals[base + s]; ai[s] = tidx[base + s]; }
    } else {
#pragma unroll
        for (int s = 0; s < 5; ++s) { a[s] = INFINITY; ai[s] = 0; }
    }
    // butterfly merge of the 16 disjoint lists (lanes 0-15 all end with the full top-5)
#pragma unroll
    for (int msk = 1; msk <= 8; msk <<= 1) {
        float bv[5]; int bi2[5];
#pragma unroll
        for (int s = 0; s < 5; ++s) {
            bv[s] = __shfl_xor(a[s], msk, 64);
            bi2[s] = __shfl_xor(ai[s], msk, 64);
        }
        merge5(a, ai, bv, bi2);
    }
    const int n0 = __shfl(ai[0], 0, 64);
    const int n1 = __shfl(ai[1], 0, 64);
    const int n2 = __shfl(ai[2], 0, 64);
    const int n3 = __shfl(ai[3], 0, 64);
    const int n4 = __shfl(ai[4], 0, 64);

    const int d0 = lane * 8;  // each lane owns 8 contiguous dims (64*8 = 512)
    float x0[8], x1[8], x2[8], x3[8], x4[8], pv[8];
    *(float4*)&x0[0] = *(const float4*)&M[(size_t)n0 * ND + d0];
    *(float4*)&x0[4] = *(const float4*)&M[(size_t)n0 * ND + d0 + 4];
    *(float4*)&x1[0] = *(const float4*)&M[(size_t)n1 * ND + d0];
    *(float4*)&x1[4] = *(const float4*)&M[(size_t)n1 * ND + d0 + 4];
    *(float4*)&x2[0] = *(const float4*)&M[(size_t)n2 * ND + d0];
    *(float4*)&x2[4] = *(const float4*)&M[(size_t)n2 * ND + d0 + 4];
    *(float4*)&x3[0] = *(const float4*)&M[(size_t)n3 * ND + d0];
    *(float4*)&x3[4] = *(const float4*)&M[(size_t)n3 * ND + d0 + 4];
    *(float4*)&x4[0] = *(const float4*)&M[(size_t)n4 * ND + d0];
    *(float4*)&x4[4] = *(const float4*)&M[(size_t)n4 * ND + d0 + 4];
    *(float4*)&pv[0] = *(const float4*)&V1[(size_t)row * ND + d0];
    *(float4*)&pv[4] = *(const float4*)&V1[(size_t)row * ND + d0 + 4];

    float lsum = 0.f;
#pragma unroll
    for (int e = 0; e < 8; ++e) {
        float mean = (x0[e] + x1[e] + x2[e] + x3[e] + x4[e]) * 0.2f;
        float e0 = x0[e] - mean, e1 = x1[e] - mean, e2 = x2[e] - mean,
              e3 = x3[e] - mean, e4 = x4[e] - mean;
        float var = (e0 * e0 + e1 * e1 + e2 * e2 + e3 * e3 + e4 * e4) * 0.25f;  // ddof=1
        float nstd = sqrtf(var);
        float pred = expf(0.5f * pv[e]);  // sqrt(exp(v))
        float df = pred - nstd;
        lsum = fmaf(df, df, lsum);
    }
#pragma unroll
    for (int off = 32; off >= 1; off >>= 1) lsum += __shfl_down(lsum, off, 64);
    if (lane == 0) partial[row] = lsum;
}

// ---------- kernel D: deterministic final reduction ----------
__global__ __launch_bounds__(256) void finalize_kernel(const float* __restrict__ partial,
                                                       float* __restrict__ out) {
    const int tid = threadIdx.x;
    double s = 0.0;
    for (int i = tid; i < NB; i += 256) s += (double)partial[i];
#pragma unroll
    for (int off = 32; off >= 1; off >>= 1) s += __shfl_down(s, off, 64);
    __shared__ double dsum[4];
    if ((tid & 63) == 0) dsum[tid >> 6] = s;
    __syncthreads();
    if (tid == 0)
        out[0] = (float)(((dsum[0] + dsum[1]) + (dsum[2] + dsum[3])) / ((double)NB * (double)ND));
}

extern "C" void kernel_launch(void* const* d_in, const int* in_sizes, int n_in,
                              void* d_out, int out_size, void* d_ws, size_t ws_size,
                              hipStream_t stream) {
    const float* mean1 = (const float*)d_in[0];
    const float* var1 = (const float*)d_in[1];

    char* ws = (char*)d_ws;
    unsigned short* Mh = (unsigned short*)ws;                                  // 4 MB
    unsigned short* Ml = (unsigned short*)(ws + (size_t)NB * ND * 2);          // 4 MB
    float* sq = (float*)(ws + (size_t)NB * ND * 4);                            // 16 KB
    float* tvals = (float*)(ws + (size_t)NB * ND * 4 + NB * 4);                // 1.31 MB
    int* tidx = (int*)(ws + (size_t)NB * ND * 4 + NB * 4 + (size_t)NB * NSPLIT * KNB * 4);
    float* partial = (float*)(ws + (size_t)NB * ND * 4 + NB * 4 + (size_t)NB * NSPLIT * KNB * 8);
    float* out = (float*)d_out;

    // allow 128 KiB dynamic LDS (idempotent; not a stream op, capture-safe)
    (void)hipFuncSetAttribute((const void*)dist_topk_kernel,
                              hipFuncAttributeMaxDynamicSharedMemorySize, 2 * LDSBUF);

    split_sumsq_kernel<<<NB / 4, 256, 0, stream>>>(mean1, Mh, Ml, sq);
    dist_topk_kernel<<<dim3(NB / BT, NB / BT), 512, 2 * LDSBUF, stream>>>(Mh, Ml, sq, tvals, tidx);
    loss_kernel<<<NB / 4, 256, 0, stream>>>(mean1, var1, tvals, tidx, partial);
    finalize_kernel<<<1, 256, 0, stream>>>(partial, out);
}

// Round 5
// 71.727 us; speedup vs baseline: 5.2216x; 1.2856x over previous
//
#include <hip/hip_runtime.h>
#include <math.h>

#define NB 4096
#define ND 512
#define BM 128
#define BN 256
#define BK 32
#define NSPLIT 16   /* NB / BN */
#define KNB 5
#define CHUNKS (ND / BK) /* 16 */
#define LDSBUF 24576     /* A:128x32 (8KB) + B:256x32 (16KB) bf16 */

typedef float f32x4 __attribute__((ext_vector_type(4)));
typedef short bf16x8 __attribute__((ext_vector_type(8)));
typedef unsigned short u16x8 __attribute__((ext_vector_type(8)));

// ---------- helpers: (value,index) predicated min/max ----------
__device__ __forceinline__ void sel_min(float av, int ai, float bv, int bi, float& ov, int& oi) {
    bool p = av <= bv;
    ov = p ? av : bv;
    oi = p ? ai : bi;
}
__device__ __forceinline__ void sel_max(float av, int ai, float bv, int bi, float& ov, int& oi) {
    bool p = av >= bv;
    ov = p ? av : bv;
    oi = p ? ai : bi;
}

// Merge two sorted-ascending 5-lists, keep 5 smallest (static network).
__device__ __forceinline__ void merge5(float (&a)[5], int (&ai)[5],
                                       const float (&b)[5], const int (&bi)[5]) {
    float c[5]; int ci[5];
    float m; int mi;
    sel_min(a[0], ai[0], b[0], bi[0], c[0], ci[0]);
    sel_max(a[0], ai[0], b[0], bi[0], m, mi);
    sel_min(a[1], ai[1], m, mi, c[1], ci[1]);
    sel_min(c[1], ci[1], b[1], bi[1], c[1], ci[1]);
    sel_max(a[1], ai[1], b[0], bi[0], m, mi);
    sel_min(a[2], ai[2], m, mi, c[2], ci[2]);
    sel_max(a[0], ai[0], b[1], bi[1], m, mi);
    sel_min(c[2], ci[2], m, mi, c[2], ci[2]);
    sel_min(c[2], ci[2], b[2], bi[2], c[2], ci[2]);
    sel_max(a[2], ai[2], b[0], bi[0], m, mi);
    sel_min(a[3], ai[3], m, mi, c[3], ci[3]);
    sel_max(a[1], ai[1], b[1], bi[1], m, mi);
    sel_min(c[3], ci[3], m, mi, c[3], ci[3]);
    sel_max(a[0], ai[0], b[2], bi[2], m, mi);
    sel_min(c[3], ci[3], m, mi, c[3], ci[3]);
    sel_min(c[3], ci[3], b[3], bi[3], c[3], ci[3]);
    sel_max(a[3], ai[3], b[0], bi[0], m, mi);
    sel_min(a[4], ai[4], m, mi, c[4], ci[4]);
    sel_max(a[2], ai[2], b[1], bi[1], m, mi);
    sel_min(c[4], ci[4], m, mi, c[4], ci[4]);
    sel_max(a[1], ai[1], b[2], bi[2], m, mi);
    sel_min(c[4], ci[4], m, mi, c[4], ci[4]);
    sel_max(a[0], ai[0], b[3], bi[3], m, mi);
    sel_min(c[4], ci[4], m, mi, c[4], ci[4]);
    sel_min(c[4], ci[4], b[4], bi[4], c[4], ci[4]);
#pragma unroll
    for (int s = 0; s < 5; ++s) { a[s] = c[s]; ai[s] = ci[s]; }
}

__device__ __forceinline__ void cswap(float& a, int& ai, float& b, int& bi) {
    float mn, mx; int mni, mxi;
    sel_min(a, ai, b, bi, mn, mni);
    sel_max(a, ai, b, bi, mx, mxi);
    a = mn; ai = mni; b = mx; bi = mxi;
}

// fp32 -> bf16 round-half-up on bit patterns (monotone)
__device__ __forceinline__ unsigned short bf16rn(float x) {
    unsigned u = __float_as_uint(x);
    return (unsigned short)((u + 0x8000u) >> 16);
}

// ---------- kernel A: global fp32 -> Mh bf16 + row sumsq ----------
__global__ __launch_bounds__(256) void split_sumsq_kernel(const float* __restrict__ M,
                                                          unsigned short* __restrict__ Mh,
                                                          float* __restrict__ sq) {
    const int row = blockIdx.x * 4 + (threadIdx.x >> 6);
    const int lane = threadIdx.x & 63;
    const float* p = M + (size_t)row * ND + lane * 8;
    float4 v0 = *(const float4*)p;
    float4 v1 = *(const float4*)(p + 4);
    u16x8 h;
    ((unsigned short*)&h)[0] = bf16rn(v0.x);
    ((unsigned short*)&h)[1] = bf16rn(v0.y);
    ((unsigned short*)&h)[2] = bf16rn(v0.z);
    ((unsigned short*)&h)[3] = bf16rn(v0.w);
    ((unsigned short*)&h)[4] = bf16rn(v1.x);
    ((unsigned short*)&h)[5] = bf16rn(v1.y);
    ((unsigned short*)&h)[6] = bf16rn(v1.z);
    ((unsigned short*)&h)[7] = bf16rn(v1.w);
    *(u16x8*)&Mh[(size_t)row * ND + lane * 8] = h;
    float s = v0.x * v0.x + v0.y * v0.y + v0.z * v0.z + v0.w * v0.w
            + v1.x * v1.x + v1.y * v1.y + v1.z * v1.z + v1.w * v1.w;
#pragma unroll
    for (int off = 32; off >= 1; off >>= 1) s += __shfl_down(s, off, 64);
    if (lane == 0) sq[row] = s;
}

// ---------- staging: 6 global_load_lds units per wave, source-swizzled ----------
// Unit u (0..23): u<8 -> A rows u*16.. ; u>=8 -> B rows (u-8)*16..
__device__ __forceinline__ void stage_chunk(const unsigned short* __restrict__ Mh,
                                            char* smem, int buf, int kc,
                                            int i0, int jb, int wid, int lane) {
#pragma unroll
    for (int s2 = 0; s2 < 6; ++s2) {
        const int u = wid * 6 + s2;
        const int isB = (u >= 8);
        const int v = isB ? (u - 8) : u;
        const int rl = v * 16 + (lane >> 2);          // tile-local row
        const int gg = (lane & 3) ^ ((rl >> 1) & 3);  // swizzled 16B slot in row
        const int grow = (isB ? jb : i0) + rl;
        const unsigned short* src = Mh + (size_t)grow * ND + kc + gg * 8;
        char* dst = smem + buf * LDSBUF + isB * 8192 + v * 1024;
        __builtin_amdgcn_global_load_lds(
            (const __attribute__((address_space(1))) void*)src,
            (__attribute__((address_space(3))) void*)dst, 16, 0, 0);
    }
}

// ---------- kernel B: MFMA (1-pass bf16) Gram tile + fused per-row top-5 ----------
__global__ __launch_bounds__(256, 2) void dist_topk_kernel(const unsigned short* __restrict__ Mh,
                                                           const float* __restrict__ sq,
                                                           float* __restrict__ tvals,
                                                           int* __restrict__ tidx) {
    extern __shared__ char smem[];
    const int tid = threadIdx.x;
    const int lane = tid & 63;
    const int wid = tid >> 6;       // 0..3
    const int wr = wid >> 1;        // wave-row 0..1 (rows wr*64)
    const int wc = wid & 1;         // wave-col 0..1 (cols wc*128)
    const int col16 = lane & 15;
    const int g = lane >> 4;        // k-group 0..3
    const int i0 = blockIdx.x * BM;
    const int jb = blockIdx.y * BN;

    f32x4 acc[4][8];
    const f32x4 zero = {0.f, 0.f, 0.f, 0.f};
#pragma unroll
    for (int m = 0; m < 4; ++m)
#pragma unroll
        for (int n = 0; n < 8; ++n) acc[m][n] = zero;

    stage_chunk(Mh, smem, 0, 0, i0, jb, wid, lane);

    for (int c = 0; c < CHUNKS; ++c) {
        const int cur = c & 1;
        __syncthreads();  // drains stage(c) + protects prev-buffer reads
        if (c + 1 < CHUNKS)
            stage_chunk(Mh, smem, cur ^ 1, (c + 1) * BK, i0, jb, wid, lane);

        const char* bp = smem + cur * LDSBUF;
        bf16x8 ah[4], bh[8];
#pragma unroll
        for (int m = 0; m < 4; ++m) {
            const int r = wr * 64 + m * 16 + col16;
            ah[m] = *(const bf16x8*)(bp + r * 64 + ((g ^ ((r >> 1) & 3)) << 4));
        }
#pragma unroll
        for (int n = 0; n < 8; ++n) {
            const int r = wc * 128 + n * 16 + col16;
            bh[n] = *(const bf16x8*)(bp + 8192 + r * 64 + ((g ^ ((r >> 1) & 3)) << 4));
        }
#pragma unroll
        for (int m = 0; m < 4; ++m)
#pragma unroll
            for (int n = 0; n < 8; ++n)
                acc[m][n] = __builtin_amdgcn_mfma_f32_16x16x32_bf16(ah[m], bh[n], acc[m][n], 0, 0, 0);
    }

    __syncthreads();  // all LDS reads done; alias selection buffers
    float* selv = (float*)smem;                 // [128][2][5]
    int* seli = (int*)(smem + BM * 2 * 5 * 4);  // [128][2][5]

    float sqj[8]; int jgv[8];
#pragma unroll
    for (int n = 0; n < 8; ++n) {
        jgv[n] = jb + wc * 128 + n * 16 + col16;
        sqj[n] = sq[jgv[n]];
    }

#pragma unroll
    for (int m = 0; m < 4; ++m) {
#pragma unroll
        for (int r = 0; r < 4; ++r) {
            const int rloc = wr * 64 + m * 16 + g * 4 + r;
            const int grow = i0 + rloc;
            float v[8]; int j[8];
#pragma unroll
            for (int n = 0; n < 8; ++n) {
                v[n] = fmaf(-2.f, acc[m][n][r], sqj[n]);  // key = sq[j] - 2*dot
                j[n] = jgv[n];
                if (j[n] == grow) v[n] = INFINITY;        // mask diagonal
            }
            // sort v0..3 and v4..7 (4-nets), then merge into top-5 of 8
            cswap(v[0], j[0], v[1], j[1]); cswap(v[2], j[2], v[3], j[3]);
            cswap(v[0], j[0], v[2], j[2]); cswap(v[1], j[1], v[3], j[3]);
            cswap(v[1], j[1], v[2], j[2]);
            cswap(v[4], j[4], v[5], j[5]); cswap(v[6], j[6], v[7], j[7]);
            cswap(v[4], j[4], v[6], j[6]); cswap(v[5], j[5], v[7], j[7]);
            cswap(v[5], j[5], v[6], j[6]);
            float tv[5] = {v[0], v[1], v[2], v[3], INFINITY};
            int ti[5] = {j[0], j[1], j[2], j[3], 0};
            float bv[5] = {v[4], v[5], v[6], v[7], INFINITY};
            int bi2[5] = {j[4], j[5], j[6], j[7], 0};
            merge5(tv, ti, bv, bi2);
            // butterfly across the 16 lanes sharing this row
#pragma unroll
            for (int msk = 1; msk <= 8; msk <<= 1) {
                float xv[5]; int xi[5];
#pragma unroll
                for (int s = 0; s < 5; ++s) {
                    xv[s] = __shfl_xor(tv[s], msk, 64);
                    xi[s] = __shfl_xor(ti[s], msk, 64);
                }
                merge5(tv, ti, xv, xi);
            }
            if (col16 == 0) {
#pragma unroll
                for (int s = 0; s < 5; ++s) {
                    selv[(rloc * 2 + wc) * 5 + s] = tv[s];
                    seli[(rloc * 2 + wc) * 5 + s] = ti[s];
                }
            }
        }
    }
    __syncthreads();
    if (tid < BM) {
        float a[5]; int ai[5];
        float b[5]; int bi2[5];
#pragma unroll
        for (int s = 0; s < 5; ++s) {
            a[s] = selv[(tid * 2 + 0) * 5 + s];
            ai[s] = seli[(tid * 2 + 0) * 5 + s];
            b[s] = selv[(tid * 2 + 1) * 5 + s];
            bi2[s] = seli[(tid * 2 + 1) * 5 + s];
        }
        merge5(a, ai, b, bi2);
        const size_t base = ((size_t)(i0 + tid) * NSPLIT + blockIdx.y) * KNB;
#pragma unroll
        for (int s = 0; s < 5; ++s) {
            tvals[base + s] = a[s];
            tidx[base + s] = ai[s];
        }
    }
}

// ---------- kernel C: one wave per row — parallel 16-list merge + std(ddof=1) + MSE ----------
__global__ __launch_bounds__(256) void loss_kernel(const float* __restrict__ M,
                                                   const float* __restrict__ V1,
                                                   const float* __restrict__ tvals,
                                                   const int* __restrict__ tidx,
                                                   float* __restrict__ partial) {
    const int row = blockIdx.x * 4 + (threadIdx.x >> 6);
    const int lane = threadIdx.x & 63;

    float a[5]; int ai[5];
    if (lane < NSPLIT) {
        const size_t base = (size_t)row * (NSPLIT * KNB) + lane * KNB;
#pragma unroll
        for (int s = 0; s < 5; ++s) { a[s] = tvals[base + s]; ai[s] = tidx[base + s]; }
    } else {
#pragma unroll
        for (int s = 0; s < 5; ++s) { a[s] = INFINITY; ai[s] = 0; }
    }
#pragma unroll
    for (int msk = 1; msk <= 8; msk <<= 1) {
        float bv[5]; int bi2[5];
#pragma unroll
        for (int s = 0; s < 5; ++s) {
            bv[s] = __shfl_xor(a[s], msk, 64);
            bi2[s] = __shfl_xor(ai[s], msk, 64);
        }
        merge5(a, ai, bv, bi2);
    }
    const int n0 = __shfl(ai[0], 0, 64);
    const int n1 = __shfl(ai[1], 0, 64);
    const int n2 = __shfl(ai[2], 0, 64);
    const int n3 = __shfl(ai[3], 0, 64);
    const int n4 = __shfl(ai[4], 0, 64);

    const int d0 = lane * 8;
    float x0[8], x1[8], x2[8], x3[8], x4[8], pv[8];
    *(float4*)&x0[0] = *(const float4*)&M[(size_t)n0 * ND + d0];
    *(float4*)&x0[4] = *(const float4*)&M[(size_t)n0 * ND + d0 + 4];
    *(float4*)&x1[0] = *(const float4*)&M[(size_t)n1 * ND + d0];
    *(float4*)&x1[4] = *(const float4*)&M[(size_t)n1 * ND + d0 + 4];
    *(float4*)&x2[0] = *(const float4*)&M[(size_t)n2 * ND + d0];
    *(float4*)&x2[4] = *(const float4*)&M[(size_t)n2 * ND + d0 + 4];
    *(float4*)&x3[0] = *(const float4*)&M[(size_t)n3 * ND + d0];
    *(float4*)&x3[4] = *(const float4*)&M[(size_t)n3 * ND + d0 + 4];
    *(float4*)&x4[0] = *(const float4*)&M[(size_t)n4 * ND + d0];
    *(float4*)&x4[4] = *(const float4*)&M[(size_t)n4 * ND + d0 + 4];
    *(float4*)&pv[0] = *(const float4*)&V1[(size_t)row * ND + d0];
    *(float4*)&pv[4] = *(const float4*)&V1[(size_t)row * ND + d0 + 4];

    float lsum = 0.f;
#pragma unroll
    for (int e = 0; e < 8; ++e) {
        float mean = (x0[e] + x1[e] + x2[e] + x3[e] + x4[e]) * 0.2f;
        float e0 = x0[e] - mean, e1 = x1[e] - mean, e2 = x2[e] - mean,
              e3 = x3[e] - mean, e4 = x4[e] - mean;
        float var = (e0 * e0 + e1 * e1 + e2 * e2 + e3 * e3 + e4 * e4) * 0.25f;  // ddof=1
        float nstd = sqrtf(var);
        float pred = expf(0.5f * pv[e]);  // sqrt(exp(v))
        float df = pred - nstd;
        lsum = fmaf(df, df, lsum);
    }
#pragma unroll
    for (int off = 32; off >= 1; off >>= 1) lsum += __shfl_down(lsum, off, 64);
    if (lane == 0) partial[row] = lsum;
}

// ---------- kernel D: deterministic final reduction ----------
__global__ __launch_bounds__(256) void finalize_kernel(const float* __restrict__ partial,
                                                       float* __restrict__ out) {
    const int tid = threadIdx.x;
    double s = 0.0;
    for (int i = tid; i < NB; i += 256) s += (double)partial[i];
#pragma unroll
    for (int off = 32; off >= 1; off >>= 1) s += __shfl_down(s, off, 64);
    __shared__ double dsum[4];
    if ((tid & 63) == 0) dsum[tid >> 6] = s;
    __syncthreads();
    if (tid == 0)
        out[0] = (float)(((dsum[0] + dsum[1]) + (dsum[2] + dsum[3])) / ((double)NB * (double)ND));
}

extern "C" void kernel_launch(void* const* d_in, const int* in_sizes, int n_in,
                              void* d_out, int out_size, void* d_ws, size_t ws_size,
                              hipStream_t stream) {
    const float* mean1 = (const float*)d_in[0];
    const float* var1 = (const float*)d_in[1];

    char* ws = (char*)d_ws;
    unsigned short* Mh = (unsigned short*)ws;                       // 4 MB
    float* sq = (float*)(ws + (size_t)NB * ND * 2);                 // 16 KB
    float* tvals = (float*)(ws + (size_t)NB * ND * 2 + NB * 4);     // 1.31 MB
    int* tidx = (int*)(ws + (size_t)NB * ND * 2 + NB * 4 + (size_t)NB * NSPLIT * KNB * 4);
    float* partial = (float*)(ws + (size_t)NB * ND * 2 + NB * 4 + (size_t)NB * NSPLIT * KNB * 8);
    float* out = (float*)d_out;

    (void)hipFuncSetAttribute((const void*)dist_topk_kernel,
                              hipFuncAttributeMaxDynamicSharedMemorySize, 2 * LDSBUF);

    split_sumsq_kernel<<<NB / 4, 256, 0, stream>>>(mean1, Mh, sq);
    dist_topk_kernel<<<dim3(NB / BM, NB / BN), 256, 2 * LDSBUF, stream>>>(Mh, sq, tvals, tidx);
    loss_kernel<<<NB / 4, 256, 0, stream>>>(mean1, var1, tvals, tidx, partial);
    finalize_kernel<<<1, 256, 0, stream>>>(partial, out);
}

// Round 6
// 50.929 us; speedup vs baseline: 7.3539x; 1.4084x over previous
//
#include <hip/hip_runtime.h>
#include <math.h>

#define NB 4096
#define ND 512
#define BM 128
#define BN 256
#define BK 32
#define NSPLIT 16   /* NB / BN */
#define KNB 5
#define CHUNKS (ND / BK) /* 16 */
#define LDSBUF 24576     /* A:128x32 (8KB) + B:256x32 (16KB) bf16 */
#define UMAXV 0xFFFFFFFFu

typedef float f32x4 __attribute__((ext_vector_type(4)));
typedef short bf16x8 __attribute__((ext_vector_type(8)));
typedef unsigned short u16x8 __attribute__((ext_vector_type(8)));

// ---------- packed (quantized-key | index) selection primitives ----------
// key: fp32 -> monotone u32 (total order), top 20 bits kept; low 12 bits = column index.
// min() on packed = (key, then smaller index) — matches stable top_k tie-break.
__device__ __forceinline__ unsigned packkey(float kf, int j) {
    unsigned uk = __float_as_uint(kf);
    uk ^= (unsigned)((int)uk >> 31) | 0x80000000u;
    return (uk & 0xFFFFF000u) | (unsigned)j;
}

__device__ __forceinline__ void uswap(unsigned& a, unsigned& b) {
    unsigned mn = min(a, b), mx = max(a, b);
    a = mn; b = mx;
}

// Merge two sorted-ascending 5-lists (packed), keep 5 smallest.
// c_i = min(a_i, b_i, min_j max(a_j, b_{i-1-j}))  — 25 min/max ops.
__device__ __forceinline__ void merge5u(unsigned (&a)[5], const unsigned (&b)[5]) {
    unsigned c0 = min(a[0], b[0]);
    unsigned c1 = min(min(a[1], max(a[0], b[0])), b[1]);
    unsigned c2 = min(min(a[2], max(a[1], b[0])), min(max(a[0], b[1]), b[2]));
    unsigned c3 = min(min(a[3], max(a[2], b[0])),
                      min(max(a[1], b[1]), min(max(a[0], b[2]), b[3])));
    unsigned c4 = min(min(a[4], max(a[3], b[0])),
                      min(max(a[2], b[1]),
                          min(max(a[1], b[2]), min(max(a[0], b[3]), b[4]))));
    a[0] = c0; a[1] = c1; a[2] = c2; a[3] = c3; a[4] = c4;
}

// fp32 -> bf16 round-half-up on bit patterns (monotone)
__device__ __forceinline__ unsigned short bf16rn(float x) {
    unsigned u = __float_as_uint(x);
    return (unsigned short)((u + 0x8000u) >> 16);
}

// ---------- kernel A: global fp32 -> Mh bf16 + row sumsq ----------
__global__ __launch_bounds__(256) void split_sumsq_kernel(const float* __restrict__ M,
                                                          unsigned short* __restrict__ Mh,
                                                          float* __restrict__ sq) {
    const int row = blockIdx.x * 4 + (threadIdx.x >> 6);
    const int lane = threadIdx.x & 63;
    const float* p = M + (size_t)row * ND + lane * 8;
    float4 v0 = *(const float4*)p;
    float4 v1 = *(const float4*)(p + 4);
    u16x8 h;
    ((unsigned short*)&h)[0] = bf16rn(v0.x);
    ((unsigned short*)&h)[1] = bf16rn(v0.y);
    ((unsigned short*)&h)[2] = bf16rn(v0.z);
    ((unsigned short*)&h)[3] = bf16rn(v0.w);
    ((unsigned short*)&h)[4] = bf16rn(v1.x);
    ((unsigned short*)&h)[5] = bf16rn(v1.y);
    ((unsigned short*)&h)[6] = bf16rn(v1.z);
    ((unsigned short*)&h)[7] = bf16rn(v1.w);
    *(u16x8*)&Mh[(size_t)row * ND + lane * 8] = h;
    float s = v0.x * v0.x + v0.y * v0.y + v0.z * v0.z + v0.w * v0.w
            + v1.x * v1.x + v1.y * v1.y + v1.z * v1.z + v1.w * v1.w;
#pragma unroll
    for (int off = 32; off >= 1; off >>= 1) s += __shfl_down(s, off, 64);
    if (lane == 0) sq[row] = s;
}

// ---------- staging: 6 global_load_lds units per wave, source-swizzled ----------
__device__ __forceinline__ void stage_chunk(const unsigned short* __restrict__ Mh,
                                            char* smem, int buf, int kc,
                                            int i0, int jb, int wid, int lane) {
#pragma unroll
    for (int s2 = 0; s2 < 6; ++s2) {
        const int u = wid * 6 + s2;
        const int isB = (u >= 8);
        const int v = isB ? (u - 8) : u;
        const int rl = v * 16 + (lane >> 2);          // tile-local row
        const int gg = (lane & 3) ^ ((rl >> 1) & 3);  // swizzled 16B slot in row
        const int grow = (isB ? jb : i0) + rl;
        const unsigned short* src = Mh + (size_t)grow * ND + kc + gg * 8;
        char* dst = smem + buf * LDSBUF + isB * 8192 + v * 1024;
        __builtin_amdgcn_global_load_lds(
            (const __attribute__((address_space(1))) void*)src,
            (__attribute__((address_space(3))) void*)dst, 16, 0, 0);
    }
}

// ---------- kernel B: MFMA (1-pass bf16) Gram tile + fused per-row top-5 ----------
__global__ __launch_bounds__(256, 2) void dist_topk_kernel(const unsigned short* __restrict__ Mh,
                                                           const float* __restrict__ sq,
                                                           unsigned* __restrict__ tvals) {
    extern __shared__ char smem[];
    const int tid = threadIdx.x;
    const int lane = tid & 63;
    const int wid = tid >> 6;       // 0..3
    const int wr = wid >> 1;        // wave-row 0..1 (rows wr*64)
    const int wc = wid & 1;         // wave-col 0..1 (cols wc*128)
    const int col16 = lane & 15;
    const int g = lane >> 4;        // k-group 0..3
    const int i0 = blockIdx.x * BM;
    const int jb = blockIdx.y * BN;

    f32x4 acc[4][8];
    const f32x4 zero = {0.f, 0.f, 0.f, 0.f};
#pragma unroll
    for (int m = 0; m < 4; ++m)
#pragma unroll
        for (int n = 0; n < 8; ++n) acc[m][n] = zero;

    stage_chunk(Mh, smem, 0, 0, i0, jb, wid, lane);

    for (int c = 0; c < CHUNKS; ++c) {
        const int cur = c & 1;
        __syncthreads();  // drains stage(c) + protects prev-buffer reads
        if (c + 1 < CHUNKS)
            stage_chunk(Mh, smem, cur ^ 1, (c + 1) * BK, i0, jb, wid, lane);

        const char* bp = smem + cur * LDSBUF;
        bf16x8 ah[4], bh[8];
#pragma unroll
        for (int m = 0; m < 4; ++m) {
            const int r = wr * 64 + m * 16 + col16;
            ah[m] = *(const bf16x8*)(bp + r * 64 + ((g ^ ((r >> 1) & 3)) << 4));
        }
#pragma unroll
        for (int n = 0; n < 8; ++n) {
            const int r = wc * 128 + n * 16 + col16;
            bh[n] = *(const bf16x8*)(bp + 8192 + r * 64 + ((g ^ ((r >> 1) & 3)) << 4));
        }
#pragma unroll
        for (int m = 0; m < 4; ++m)
#pragma unroll
            for (int n = 0; n < 8; ++n)
                acc[m][n] = __builtin_amdgcn_mfma_f32_16x16x32_bf16(ah[m], bh[n], acc[m][n], 0, 0, 0);
    }

    __syncthreads();  // all LDS reads done; alias selection buffer
    unsigned* selp = (unsigned*)smem;  // [128][2][5] packed

    float sqj[8]; int jgv[8];
#pragma unroll
    for (int n = 0; n < 8; ++n) {
        jgv[n] = jb + wc * 128 + n * 16 + col16;
        sqj[n] = sq[jgv[n]];
    }

#pragma unroll
    for (int m = 0; m < 4; ++m) {
#pragma unroll
        for (int r = 0; r < 4; ++r) {
            const int rloc = wr * 64 + m * 16 + g * 4 + r;
            const int grow = i0 + rloc;
            unsigned p0, p1, p2, p3, p4, p5, p6, p7;
            // key = sq[j] - 2*dot  (monotone in d^2 per row)
            p0 = packkey(fmaf(-2.f, acc[m][0][r], sqj[0]), jgv[0]);
            p1 = packkey(fmaf(-2.f, acc[m][1][r], sqj[1]), jgv[1]);
            p2 = packkey(fmaf(-2.f, acc[m][2][r], sqj[2]), jgv[2]);
            p3 = packkey(fmaf(-2.f, acc[m][3][r], sqj[3]), jgv[3]);
            p4 = packkey(fmaf(-2.f, acc[m][4][r], sqj[4]), jgv[4]);
            p5 = packkey(fmaf(-2.f, acc[m][5][r], sqj[5]), jgv[5]);
            p6 = packkey(fmaf(-2.f, acc[m][6][r], sqj[6]), jgv[6]);
            p7 = packkey(fmaf(-2.f, acc[m][7][r], sqj[7]), jgv[7]);
            if (jgv[0] == grow) p0 = UMAXV;  // mask diagonal
            if (jgv[1] == grow) p1 = UMAXV;
            if (jgv[2] == grow) p2 = UMAXV;
            if (jgv[3] == grow) p3 = UMAXV;
            if (jgv[4] == grow) p4 = UMAXV;
            if (jgv[5] == grow) p5 = UMAXV;
            if (jgv[6] == grow) p6 = UMAXV;
            if (jgv[7] == grow) p7 = UMAXV;
            // sort p0..3 and p4..7 (4-nets), then merge into top-5 of 8
            uswap(p0, p1); uswap(p2, p3); uswap(p0, p2); uswap(p1, p3); uswap(p1, p2);
            uswap(p4, p5); uswap(p6, p7); uswap(p4, p6); uswap(p5, p7); uswap(p5, p6);
            unsigned tv[5] = {p0, p1, p2, p3, UMAXV};
            unsigned bv[5] = {p4, p5, p6, p7, UMAXV};
            merge5u(tv, bv);
            // butterfly across the 16 lanes sharing this row
#pragma unroll
            for (int msk = 1; msk <= 8; msk <<= 1) {
                unsigned xv[5];
#pragma unroll
                for (int s = 0; s < 5; ++s) xv[s] = __shfl_xor(tv[s], msk, 64);
                merge5u(tv, xv);
            }
            if (col16 == 0) {
#pragma unroll
                for (int s = 0; s < 5; ++s) selp[(rloc * 2 + wc) * 5 + s] = tv[s];
            }
        }
    }
    __syncthreads();
    if (tid < BM) {
        unsigned a[5], b[5];
#pragma unroll
        for (int s = 0; s < 5; ++s) {
            a[s] = selp[(tid * 2 + 0) * 5 + s];
            b[s] = selp[(tid * 2 + 1) * 5 + s];
        }
        merge5u(a, b);
        const size_t base = ((size_t)(i0 + tid) * NSPLIT + blockIdx.y) * KNB;
#pragma unroll
        for (int s = 0; s < 5; ++s) tvals[base + s] = a[s];
    }
}

// ---------- kernel C: one wave per row — packed 16-list merge + std(ddof=1) + MSE ----------
__global__ __launch_bounds__(256) void loss_kernel(const float* __restrict__ M,
                                                   const float* __restrict__ V1,
                                                   const unsigned* __restrict__ tvals,
                                                   float* __restrict__ partial) {
    const int row = blockIdx.x * 4 + (threadIdx.x >> 6);
    const int lane = threadIdx.x & 63;

    unsigned a[5];
    if (lane < NSPLIT) {
        const size_t base = (size_t)row * (NSPLIT * KNB) + lane * KNB;
#pragma unroll
        for (int s = 0; s < 5; ++s) a[s] = tvals[base + s];
    } else {
#pragma unroll
        for (int s = 0; s < 5; ++s) a[s] = UMAXV;
    }
#pragma unroll
    for (int msk = 1; msk <= 8; msk <<= 1) {
        unsigned bv[5];
#pragma unroll
        for (int s = 0; s < 5; ++s) bv[s] = __shfl_xor(a[s], msk, 64);
        merge5u(a, bv);
    }
    const int n0 = __shfl((int)(a[0] & 0xFFFu), 0, 64);
    const int n1 = __shfl((int)(a[1] & 0xFFFu), 0, 64);
    const int n2 = __shfl((int)(a[2] & 0xFFFu), 0, 64);
    const int n3 = __shfl((int)(a[3] & 0xFFFu), 0, 64);
    const int n4 = __shfl((int)(a[4] & 0xFFFu), 0, 64);

    const int d0 = lane * 8;
    float x0[8], x1[8], x2[8], x3[8], x4[8], pv[8];
    *(float4*)&x0[0] = *(const float4*)&M[(size_t)n0 * ND + d0];
    *(float4*)&x0[4] = *(const float4*)&M[(size_t)n0 * ND + d0 + 4];
    *(float4*)&x1[0] = *(const float4*)&M[(size_t)n1 * ND + d0];
    *(float4*)&x1[4] = *(const float4*)&M[(size_t)n1 * ND + d0 + 4];
    *(float4*)&x2[0] = *(const float4*)&M[(size_t)n2 * ND + d0];
    *(float4*)&x2[4] = *(const float4*)&M[(size_t)n2 * ND + d0 + 4];
    *(float4*)&x3[0] = *(const float4*)&M[(size_t)n3 * ND + d0];
    *(float4*)&x3[4] = *(const float4*)&M[(size_t)n3 * ND + d0 + 4];
    *(float4*)&x4[0] = *(const float4*)&M[(size_t)n4 * ND + d0];
    *(float4*)&x4[4] = *(const float4*)&M[(size_t)n4 * ND + d0 + 4];
    *(float4*)&pv[0] = *(const float4*)&V1[(size_t)row * ND + d0];
    *(float4*)&pv[4] = *(const float4*)&V1[(size_t)row * ND + d0 + 4];

    float lsum = 0.f;
#pragma unroll
    for (int e = 0; e < 8; ++e) {
        float mean = (x0[e] + x1[e] + x2[e] + x3[e] + x4[e]) * 0.2f;
        float e0 = x0[e] - mean, e1 = x1[e] - mean, e2 = x2[e] - mean,
              e3 = x3[e] - mean, e4 = x4[e] - mean;
        float var = (e0 * e0 + e1 * e1 + e2 * e2 + e3 * e3 + e4 * e4) * 0.25f;  // ddof=1
        float nstd = sqrtf(var);
        float pred = expf(0.5f * pv[e]);  // sqrt(exp(v))
        float df = pred - nstd;
        lsum = fmaf(df, df, lsum);
    }
#pragma unroll
    for (int off = 32; off >= 1; off >>= 1) lsum += __shfl_down(lsum, off, 64);
    if (lane == 0) partial[row] = lsum;
}

// ---------- kernel D: deterministic final reduction ----------
__global__ __launch_bounds__(256) void finalize_kernel(const float* __restrict__ partial,
                                                       float* __restrict__ out) {
    const int tid = threadIdx.x;
    double s = 0.0;
    for (int i = tid; i < NB; i += 256) s += (double)partial[i];
#pragma unroll
    for (int off = 32; off >= 1; off >>= 1) s += __shfl_down(s, off, 64);
    __shared__ double dsum[4];
    if ((tid & 63) == 0) dsum[tid >> 6] = s;
    __syncthreads();
    if (tid == 0)
        out[0] = (float)(((dsum[0] + dsum[1]) + (dsum[2] + dsum[3])) / ((double)NB * (double)ND));
}

extern "C" void kernel_launch(void* const* d_in, const int* in_sizes, int n_in,
                              void* d_out, int out_size, void* d_ws, size_t ws_size,
                              hipStream_t stream) {
    const float* mean1 = (const float*)d_in[0];
    const float* var1 = (const float*)d_in[1];

    char* ws = (char*)d_ws;
    unsigned short* Mh = (unsigned short*)ws;                          // 4 MB
    float* sq = (float*)(ws + (size_t)NB * ND * 2);                    // 16 KB
    unsigned* tvals = (unsigned*)(ws + (size_t)NB * ND * 2 + NB * 4);  // 1.31 MB packed
    float* partial = (float*)(ws + (size_t)NB * ND * 2 + NB * 4 + (size_t)NB * NSPLIT * KNB * 4);
    float* out = (float*)d_out;

    (void)hipFuncSetAttribute((const void*)dist_topk_kernel,
                              hipFuncAttributeMaxDynamicSharedMemorySize, 2 * LDSBUF);

    split_sumsq_kernel<<<NB / 4, 256, 0, stream>>>(mean1, Mh, sq);
    dist_topk_kernel<<<dim3(NB / BM, NB / BN), 256, 2 * LDSBUF, stream>>>(Mh, sq, tvals);
    loss_kernel<<<NB / 4, 256, 0, stream>>>(mean1, var1, tvals, partial);
    finalize_kernel<<<1, 256, 0, stream>>>(partial, out);
}

// Round 7
// 45.813 us; speedup vs baseline: 8.1751x; 1.1117x over previous
//
#include <hip/hip_runtime.h>
#include <math.h>

#define NB 4096
#define ND 512
#define BM 128
#define BN 256
#define BK 32
#define NSPLIT 16   /* NB / BN */
#define KNB 5
#define CHUNKS (ND / BK) /* 16 */
#define LDSBUF 24576     /* A:128x32 (8KB) + B:256x32 (16KB) bf16 */
#define UMAXV 0xFFFFFFFFu

typedef float f32x4 __attribute__((ext_vector_type(4)));
typedef short bf16x8 __attribute__((ext_vector_type(8)));
typedef unsigned short u16x8 __attribute__((ext_vector_type(8)));

// ---------- packed (quantized-key | index) selection primitives ----------
// key: fp32 -> monotone u32 (total order), top 20 bits kept; low 12 bits = column index.
// min() on packed = (key, then smaller index) — matches stable top_k tie-break.
__device__ __forceinline__ unsigned packkey(float kf, int j) {
    unsigned uk = __float_as_uint(kf);
    uk ^= (unsigned)((int)uk >> 31) | 0x80000000u;
    return (uk & 0xFFFFF000u) | (unsigned)j;
}

__device__ __forceinline__ void uswap(unsigned& a, unsigned& b) {
    unsigned mn = min(a, b), mx = max(a, b);
    a = mn; b = mx;
}

// Merge two sorted-ascending 5-lists (packed), keep 5 smallest — 25 min/max ops.
__device__ __forceinline__ void merge5u(unsigned (&a)[5], const unsigned (&b)[5]) {
    unsigned c0 = min(a[0], b[0]);
    unsigned c1 = min(min(a[1], max(a[0], b[0])), b[1]);
    unsigned c2 = min(min(a[2], max(a[1], b[0])), min(max(a[0], b[1]), b[2]));
    unsigned c3 = min(min(a[3], max(a[2], b[0])),
                      min(max(a[1], b[1]), min(max(a[0], b[2]), b[3])));
    unsigned c4 = min(min(a[4], max(a[3], b[0])),
                      min(max(a[2], b[1]),
                          min(max(a[1], b[2]), min(max(a[0], b[3]), b[4]))));
    a[0] = c0; a[1] = c1; a[2] = c2; a[3] = c3; a[4] = c4;
}

// fp32 -> bf16 round-half-up on bit patterns (monotone)
__device__ __forceinline__ unsigned short bf16rn(float x) {
    unsigned u = __float_as_uint(x);
    return (unsigned short)((u + 0x8000u) >> 16);
}

// ---------- kernel A: global fp32 -> Mh bf16 + row sumsq ----------
__global__ __launch_bounds__(256) void split_sumsq_kernel(const float* __restrict__ M,
                                                          unsigned short* __restrict__ Mh,
                                                          float* __restrict__ sq) {
    const int row = blockIdx.x * 4 + (threadIdx.x >> 6);
    const int lane = threadIdx.x & 63;
    const float* p = M + (size_t)row * ND + lane * 8;
    float4 v0 = *(const float4*)p;
    float4 v1 = *(const float4*)(p + 4);
    u16x8 h;
    ((unsigned short*)&h)[0] = bf16rn(v0.x);
    ((unsigned short*)&h)[1] = bf16rn(v0.y);
    ((unsigned short*)&h)[2] = bf16rn(v0.z);
    ((unsigned short*)&h)[3] = bf16rn(v0.w);
    ((unsigned short*)&h)[4] = bf16rn(v1.x);
    ((unsigned short*)&h)[5] = bf16rn(v1.y);
    ((unsigned short*)&h)[6] = bf16rn(v1.z);
    ((unsigned short*)&h)[7] = bf16rn(v1.w);
    *(u16x8*)&Mh[(size_t)row * ND + lane * 8] = h;
    float s = v0.x * v0.x + v0.y * v0.y + v0.z * v0.z + v0.w * v0.w
            + v1.x * v1.x + v1.y * v1.y + v1.z * v1.z + v1.w * v1.w;
#pragma unroll
    for (int off = 32; off >= 1; off >>= 1) s += __shfl_down(s, off, 64);
    if (lane == 0) sq[row] = s;
}

// ---------- staging: 6 global_load_lds units per wave, source-swizzled ----------
__device__ __forceinline__ void stage_chunk(const unsigned short* __restrict__ Mh,
                                            char* smem, int buf, int kc,
                                            int i0, int jb, int wid, int lane) {
#pragma unroll
    for (int s2 = 0; s2 < 6; ++s2) {
        const int u = wid * 6 + s2;
        const int isB = (u >= 8);
        const int v = isB ? (u - 8) : u;
        const int rl = v * 16 + (lane >> 2);          // tile-local row
        const int gg = (lane & 3) ^ ((rl >> 1) & 3);  // swizzled 16B slot in row
        const int grow = (isB ? jb : i0) + rl;
        const unsigned short* src = Mh + (size_t)grow * ND + kc + gg * 8;
        char* dst = smem + buf * LDSBUF + isB * 8192 + v * 1024;
        __builtin_amdgcn_global_load_lds(
            (const __attribute__((address_space(1))) void*)src,
            (__attribute__((address_space(3))) void*)dst, 16, 0, 0);
    }
}

// ---------- kernel B: MFMA (1-pass bf16, swapped operands) + fused per-row top-5 ----------
// Swapped MFMA: acc[m][n] = B_frag(n) x A_frag(m) -> D[j-rows][i-cols]:
//   lane's col16 = i (within frag m), regs r + k-group g = j (within frag n).
// Each lane owns 4 full i-rows with 32 j-candidates in-register -> selection
// is an in-register merge tree + only 2 shfl butterfly rounds (over g).
__global__ __launch_bounds__(256, 2) void dist_topk_kernel(const unsigned short* __restrict__ Mh,
                                                           const float* __restrict__ sq,
                                                           unsigned* __restrict__ tvals) {
    extern __shared__ char smem[];
    const int tid = threadIdx.x;
    const int lane = tid & 63;
    const int wid = tid >> 6;       // 0..3
    const int wr = wid >> 1;        // wave-row 0..1 (i rows wr*64)
    const int wc = wid & 1;         // wave-col 0..1 (j cols wc*128)
    const int col16 = lane & 15;
    const int g = lane >> 4;        // k-group 0..3
    const int i0 = blockIdx.x * BM;
    const int jb = blockIdx.y * BN;

    f32x4 acc[4][8];
    const f32x4 zero = {0.f, 0.f, 0.f, 0.f};
#pragma unroll
    for (int m = 0; m < 4; ++m)
#pragma unroll
        for (int n = 0; n < 8; ++n) acc[m][n] = zero;

    stage_chunk(Mh, smem, 0, 0, i0, jb, wid, lane);

    for (int c = 0; c < CHUNKS; ++c) {
        const int cur = c & 1;
        __syncthreads();  // drains stage(c) + protects prev-buffer reads
        if (c + 1 < CHUNKS)
            stage_chunk(Mh, smem, cur ^ 1, (c + 1) * BK, i0, jb, wid, lane);

        const char* bp = smem + cur * LDSBUF;
        bf16x8 ah[4], bh[8];
#pragma unroll
        for (int m = 0; m < 4; ++m) {
            const int r = wr * 64 + m * 16 + col16;
            ah[m] = *(const bf16x8*)(bp + r * 64 + ((g ^ ((r >> 1) & 3)) << 4));
        }
#pragma unroll
        for (int n = 0; n < 8; ++n) {
            const int r = wc * 128 + n * 16 + col16;
            bh[n] = *(const bf16x8*)(bp + 8192 + r * 64 + ((g ^ ((r >> 1) & 3)) << 4));
        }
        // swapped operands: D[j][i] — i rides the lane (col) axis
#pragma unroll
        for (int m = 0; m < 4; ++m)
#pragma unroll
            for (int n = 0; n < 8; ++n)
                acc[m][n] = __builtin_amdgcn_mfma_f32_16x16x32_bf16(bh[n], ah[m], acc[m][n], 0, 0, 0);
    }

    __syncthreads();  // all LDS reads done; alias selection buffer
    unsigned* selp = (unsigned*)smem;  // [128][2][5] packed

    // sq[j] for this lane's 32 j-candidates: j = jb + wc*128 + n*16 + g*4 + r
    float4 sqv[8];
#pragma unroll
    for (int n = 0; n < 8; ++n)
        sqv[n] = *(const float4*)&sq[jb + wc * 128 + n * 16 + g * 4];

    const bool diag = (jb < i0 + BM) && (i0 < jb + BN);  // wave-uniform

#pragma unroll
    for (int m = 0; m < 4; ++m) {
        const int ig = i0 + wr * 64 + m * 16 + col16;  // this lane's global i row
        unsigned run[5] = {UMAXV, UMAXV, UMAXV, UMAXV, UMAXV};
#pragma unroll
        for (int n = 0; n < 8; ++n) {
            const int jg0 = jb + wc * 128 + n * 16 + g * 4;
            // key = sq[j] - 2*dot  (monotone in d^2 per row i)
            unsigned q0 = packkey(fmaf(-2.f, acc[m][n][0], sqv[n].x), jg0 + 0);
            unsigned q1 = packkey(fmaf(-2.f, acc[m][n][1], sqv[n].y), jg0 + 1);
            unsigned q2 = packkey(fmaf(-2.f, acc[m][n][2], sqv[n].z), jg0 + 2);
            unsigned q3 = packkey(fmaf(-2.f, acc[m][n][3], sqv[n].w), jg0 + 3);
            if (diag) {  // mask diagonal (only possible in near-diagonal tiles)
                if (jg0 + 0 == ig) q0 = UMAXV;
                if (jg0 + 1 == ig) q1 = UMAXV;
                if (jg0 + 2 == ig) q2 = UMAXV;
                if (jg0 + 3 == ig) q3 = UMAXV;
            }
            uswap(q0, q1); uswap(q2, q3); uswap(q0, q2); uswap(q1, q3); uswap(q1, q2);
            unsigned curl[5] = {q0, q1, q2, q3, UMAXV};
            merge5u(run, curl);
        }
        // butterfly across the 4 k-group lanes sharing this i (xor 16, 32)
#pragma unroll
        for (int msk = 16; msk <= 32; msk <<= 1) {
            unsigned xv[5];
#pragma unroll
            for (int s = 0; s < 5; ++s) xv[s] = __shfl_xor(run[s], msk, 64);
            merge5u(run, xv);
        }
        if (g == 0) {
            const int rloc = wr * 64 + m * 16 + col16;
#pragma unroll
            for (int s = 0; s < 5; ++s) selp[(rloc * 2 + wc) * 5 + s] = run[s];
        }
    }
    __syncthreads();
    if (tid < BM) {
        unsigned a[5], b[5];
#pragma unroll
        for (int s = 0; s < 5; ++s) {
            a[s] = selp[(tid * 2 + 0) * 5 + s];
            b[s] = selp[(tid * 2 + 1) * 5 + s];
        }
        merge5u(a, b);
        const size_t base = ((size_t)(i0 + tid) * NSPLIT + blockIdx.y) * KNB;
#pragma unroll
        for (int s = 0; s < 5; ++s) tvals[base + s] = a[s];
    }
}

// ---------- kernel C: one wave per row — packed 16-list merge + std(ddof=1) + MSE ----------
__global__ __launch_bounds__(256) void loss_kernel(const float* __restrict__ M,
                                                   const float* __restrict__ V1,
                                                   const unsigned* __restrict__ tvals,
                                                   float* __restrict__ partial) {
    const int row = blockIdx.x * 4 + (threadIdx.x >> 6);
    const int lane = threadIdx.x & 63;

    unsigned a[5];
    if (lane < NSPLIT) {
        const size_t base = (size_t)row * (NSPLIT * KNB) + lane * KNB;
#pragma unroll
        for (int s = 0; s < 5; ++s) a[s] = tvals[base + s];
    } else {
#pragma unroll
        for (int s = 0; s < 5; ++s) a[s] = UMAXV;
    }
#pragma unroll
    for (int msk = 1; msk <= 8; msk <<= 1) {
        unsigned bv[5];
#pragma unroll
        for (int s = 0; s < 5; ++s) bv[s] = __shfl_xor(a[s], msk, 64);
        merge5u(a, bv);
    }
    const int n0 = __shfl((int)(a[0] & 0xFFFu), 0, 64);
    const int n1 = __shfl((int)(a[1] & 0xFFFu), 0, 64);
    const int n2 = __shfl((int)(a[2] & 0xFFFu), 0, 64);
    const int n3 = __shfl((int)(a[3] & 0xFFFu), 0, 64);
    const int n4 = __shfl((int)(a[4] & 0xFFFu), 0, 64);

    const int d0 = lane * 8;
    float x0[8], x1[8], x2[8], x3[8], x4[8], pv[8];
    *(float4*)&x0[0] = *(const float4*)&M[(size_t)n0 * ND + d0];
    *(float4*)&x0[4] = *(const float4*)&M[(size_t)n0 * ND + d0 + 4];
    *(float4*)&x1[0] = *(const float4*)&M[(size_t)n1 * ND + d0];
    *(float4*)&x1[4] = *(const float4*)&M[(size_t)n1 * ND + d0 + 4];
    *(float4*)&x2[0] = *(const float4*)&M[(size_t)n2 * ND + d0];
    *(float4*)&x2[4] = *(const float4*)&M[(size_t)n2 * ND + d0 + 4];
    *(float4*)&x3[0] = *(const float4*)&M[(size_t)n3 * ND + d0];
    *(float4*)&x3[4] = *(const float4*)&M[(size_t)n3 * ND + d0 + 4];
    *(float4*)&x4[0] = *(const float4*)&M[(size_t)n4 * ND + d0];
    *(float4*)&x4[4] = *(const float4*)&M[(size_t)n4 * ND + d0 + 4];
    *(float4*)&pv[0] = *(const float4*)&V1[(size_t)row * ND + d0];
    *(float4*)&pv[4] = *(const float4*)&V1[(size_t)row * ND + d0 + 4];

    float lsum = 0.f;
#pragma unroll
    for (int e = 0; e < 8; ++e) {
        float mean = (x0[e] + x1[e] + x2[e] + x3[e] + x4[e]) * 0.2f;
        float e0 = x0[e] - mean, e1 = x1[e] - mean, e2 = x2[e] - mean,
              e3 = x3[e] - mean, e4 = x4[e] - mean;
        float var = (e0 * e0 + e1 * e1 + e2 * e2 + e3 * e3 + e4 * e4) * 0.25f;  // ddof=1
        float nstd = sqrtf(var);
        float pred = expf(0.5f * pv[e]);  // sqrt(exp(v))
        float df = pred - nstd;
        lsum = fmaf(df, df, lsum);
    }
#pragma unroll
    for (int off = 32; off >= 1; off >>= 1) lsum += __shfl_down(lsum, off, 64);
    if (lane == 0) partial[row] = lsum;
}

// ---------- kernel D: deterministic final reduction ----------
__global__ __launch_bounds__(256) void finalize_kernel(const float* __restrict__ partial,
                                                       float* __restrict__ out) {
    const int tid = threadIdx.x;
    double s = 0.0;
    for (int i = tid; i < NB; i += 256) s += (double)partial[i];
#pragma unroll
    for (int off = 32; off >= 1; off >>= 1) s += __shfl_down(s, off, 64);
    __shared__ double dsum[4];
    if ((tid & 63) == 0) dsum[tid >> 6] = s;
    __syncthreads();
    if (tid == 0)
        out[0] = (float)(((dsum[0] + dsum[1]) + (dsum[2] + dsum[3])) / ((double)NB * (double)ND));
}

extern "C" void kernel_launch(void* const* d_in, const int* in_sizes, int n_in,
                              void* d_out, int out_size, void* d_ws, size_t ws_size,
                              hipStream_t stream) {
    const float* mean1 = (const float*)d_in[0];
    const float* var1 = (const float*)d_in[1];

    char* ws = (char*)d_ws;
    unsigned short* Mh = (unsigned short*)ws;                          // 4 MB
    float* sq = (float*)(ws + (size_t)NB * ND * 2);                    // 16 KB
    unsigned* tvals = (unsigned*)(ws + (size_t)NB * ND * 2 + NB * 4);  // 1.31 MB packed
    float* partial = (float*)(ws + (size_t)NB * ND * 2 + NB * 4 + (size_t)NB * NSPLIT * KNB * 4);
    float* out = (float*)d_out;

    (void)hipFuncSetAttribute((const void*)dist_topk_kernel,
                              hipFuncAttributeMaxDynamicSharedMemorySize, 2 * LDSBUF);

    split_sumsq_kernel<<<NB / 4, 256, 0, stream>>>(mean1, Mh, sq);
    dist_topk_kernel<<<dim3(NB / BM, NB / BN), 256, 2 * LDSBUF, stream>>>(Mh, sq, tvals);
    loss_kernel<<<NB / 4, 256, 0, stream>>>(mean1, var1, tvals, partial);
    finalize_kernel<<<1, 256, 0, stream>>>(partial, out);
}